// Round 1
// baseline (1992.259 us; speedup 1.0000x reference)
//
#include <hip/hip_runtime.h>
#include <math.h>

// Problem constants (fixed by setup_inputs)
#define N_ATOMS 60000
#define M_NBR   12
#define NBF     41      // nbr feature len
#define FDIM    64
#define B_CRYS  2048
#define EPSBN   1e-5f

__device__ __forceinline__ float sp(float x) {
  // softplus, stable
  return (x > 15.f) ? x : __logf(1.f + __expf(x));
}
__device__ __forceinline__ float sig(float x) {
  return 1.f / (1.f + __expf(-x));
}

// ---------------------------------------------------------------------------
// x = atom_fea @ W_embed + b_embed    [60000,92]@[92,64]
// wave-per-atom, lane t owns output col t; W in registers (92 VGPRs),
// atom row read as broadcast float4 (row is 368B, 16B aligned).
// ---------------------------------------------------------------------------
__global__ __launch_bounds__(256) void k_embed(
    const float* __restrict__ A, const float* __restrict__ W,
    const float* __restrict__ bias, float* __restrict__ X) {
  const int t = threadIdx.x & 63;
  const int w = threadIdx.x >> 6;
  float Wr[92];
#pragma unroll
  for (int k = 0; k < 92; ++k) Wr[k] = W[k * 64 + t];
  const float bv = bias[t];
  const int stride = gridDim.x * 4;
  for (int n = blockIdx.x * 4 + w; n < N_ATOMS; n += stride) {
    const float4* Ar = (const float4*)(A + (size_t)n * 92);
    float a0 = bv, a1 = 0.f;
#pragma unroll
    for (int q = 0; q < 23; ++q) {
      float4 f = Ar[q];
      a0 += f.x * Wr[4 * q]     + f.y * Wr[4 * q + 1];
      a1 += f.z * Wr[4 * q + 2] + f.w * Wr[4 * q + 3];
    }
    X[(size_t)n * 64 + t] = a0 + a1;
  }
}

// ---------------------------------------------------------------------------
// Per-atom linear parts of the conv layer, bn1 pre-folded into weights:
//   blockIdx.y==0: Yself[n,c] = (x[n]@W[0:64])[c]*s1[c] + (b[c]*s1[c]+b1[c])
//   blockIdx.y==1: Ynbr [n,c] = (x[n]@W[64:128])[c]*s1[c]
// wave-per-atom, lane t owns cols t and t+64 (128 W VGPRs).
// ---------------------------------------------------------------------------
__global__ __launch_bounds__(256) void k_lin(
    const float* __restrict__ X, const float* __restrict__ Wc,
    const float* __restrict__ bc, const float* __restrict__ g1,
    const float* __restrict__ b1, float* __restrict__ Yself,
    float* __restrict__ Ynbr) {
  const int t = threadIdx.x & 63;
  const int w = threadIdx.x >> 6;
  const bool selfp = (blockIdx.y == 0);
  const float inv = rsqrtf(1.f + EPSBN);
  const int c0 = t, c1 = t + 64;
  const float s0 = g1[c0] * inv, s1 = g1[c1] * inv;
  const float o0 = selfp ? (bc[c0] * s0 + b1[c0]) : 0.f;
  const float o1 = selfp ? (bc[c1] * s1 + b1[c1]) : 0.f;
  const float* Wp = Wc + (selfp ? 0 : 64 * 128);
  float* __restrict__ Y = selfp ? Yself : Ynbr;
  float W0[64], W1[64];
#pragma unroll
  for (int k = 0; k < 64; ++k) {
    W0[k] = Wp[k * 128 + c0] * s0;
    W1[k] = Wp[k * 128 + c1] * s1;
  }
  const int stride = gridDim.x * 4;
  for (int n = blockIdx.x * 4 + w; n < N_ATOMS; n += stride) {
    const float4* Xr = (const float4*)(X + (size_t)n * 64);
    float p0 = o0, p1 = o1, q0 = 0.f, q1 = 0.f;
#pragma unroll
    for (int q = 0; q < 16; ++q) {
      float4 f = Xr[q];
      p0 += f.x * W0[4 * q]     + f.y * W0[4 * q + 1];
      q0 += f.z * W0[4 * q + 2] + f.w * W0[4 * q + 3];
      p1 += f.x * W1[4 * q]     + f.y * W1[4 * q + 1];
      q1 += f.z * W1[4 * q + 2] + f.w * W1[4 * q + 3];
    }
    Y[(size_t)n * 128 + c0] = p0 + q0;
    Y[(size_t)n * 128 + c1] = p1 + q1;
  }
}

// ---------------------------------------------------------------------------
// Fused conv tail, IN-PLACE on X:
//   for m: g = Yself[n] + Ynbr[idx[n,m]] + nbr_fea[n,m]@(W_edge*s1)
//   acc = sum_m sigmoid(g[0:64]) * softplus(g[64:128])
//   X[n] = softplus(X[n] + acc*s2 + b2)
// wave-per-atom; W_edge (bn1-folded) in 88 VGPRs; nbr_fea rows staged into
// per-wave LDS (padded 41->44 so float4 reads are 16B aligned; pads zeroed,
// matching zero-padded W regs). Wave-synchronous LDS (in-order DS per wave).
// ---------------------------------------------------------------------------
__global__ __launch_bounds__(256) void k_conv(
    float* __restrict__ X, const float* __restrict__ Ys,
    const float* __restrict__ Yn, const float* __restrict__ NF,
    const int* __restrict__ IDX, const float* __restrict__ Wc,
    const float* __restrict__ g1, const float* __restrict__ g2,
    const float* __restrict__ b2) {
  __shared__ __align__(16) float fbuf[4][12 * 44];
  const int t = threadIdx.x & 63;
  const int w = threadIdx.x >> 6;
  const float inv = rsqrtf(1.f + EPSBN);
  const float s0 = g1[t] * inv, s1 = g1[t + 64] * inv;
  float We0[44], We1[44];
#pragma unroll
  for (int k = 0; k < 44; ++k) {
    if (k < NBF) {
      We0[k] = Wc[(128 + k) * 128 + t] * s0;
      We1[k] = Wc[(128 + k) * 128 + 64 + t] * s1;
    } else {
      We0[k] = 0.f;
      We1[k] = 0.f;
    }
  }
  const float s2 = g2[t] * inv, o2 = b2[t];
  float* fb = fbuf[w];
  const int stride = gridDim.x * 4;
  for (int n = blockIdx.x * 4 + w; n < N_ATOMS; n += stride) {
    const float* src = NF + (size_t)n * (M_NBR * NBF);
#pragma unroll
    for (int l = 0; l < 8; ++l) {
      int i = t + l * 64;
      if (i < M_NBR * NBF) fb[(i / NBF) * 44 + (i % NBF)] = src[i];
    }
    if (t < M_NBR) {
      fb[t * 44 + 41] = 0.f;
      fb[t * 44 + 42] = 0.f;
      fb[t * 44 + 43] = 0.f;
    }
    const float ys0 = Ys[(size_t)n * 128 + t];
    const float ys1 = Ys[(size_t)n * 128 + 64 + t];
    const int4* ir = (const int4*)(IDX + (size_t)n * M_NBR);
    const int4 ia = ir[0], ib = ir[1], ic = ir[2];
    const int jj[12] = {ia.x, ia.y, ia.z, ia.w, ib.x, ib.y,
                        ib.z, ib.w, ic.x, ic.y, ic.z, ic.w};
    float acc = 0.f;
#pragma unroll
    for (int m = 0; m < M_NBR; ++m) {
      const int j = jj[m];
      float g0 = ys0 + Yn[(size_t)j * 128 + t];
      float h1 = ys1 + Yn[(size_t)j * 128 + 64 + t];
      float g0b = 0.f, h1b = 0.f;
      const float4* fq = (const float4*)(fb + m * 44);
#pragma unroll
      for (int q = 0; q < 11; ++q) {
        float4 f = fq[q];
        g0  += f.x * We0[4 * q]     + f.y * We0[4 * q + 1];
        g0b += f.z * We0[4 * q + 2] + f.w * We0[4 * q + 3];
        h1  += f.x * We1[4 * q]     + f.y * We1[4 * q + 1];
        h1b += f.z * We1[4 * q + 2] + f.w * We1[4 * q + 3];
      }
      acc += sig(g0 + g0b) * sp(h1 + h1b);
    }
    const float ns = acc * s2 + o2;
    const float xv = X[(size_t)n * 64 + t];
    X[(size_t)n * 64 + t] = sp(xv + ns);
  }
}

// ---------------------------------------------------------------------------
// Fused: segment-mean pool (binary search on sorted segment_ids) + extra
// embedding + conv_to_fc + 3 output heads (incl. log_softmax).
// One block of 128 threads per crystal.
// ---------------------------------------------------------------------------
__device__ __forceinline__ int lbound(const int* __restrict__ a, int n, int v) {
  int lo = 0, hi = n;
  while (lo < hi) {
    int mid = (lo + hi) >> 1;
    if (a[mid] < v) lo = mid + 1; else hi = mid;
  }
  return lo;
}

__global__ __launch_bounds__(128) void k_head(
    const float* __restrict__ Xf, const int* __restrict__ seg,
    const float* __restrict__ EF, const float* __restrict__ Wx,
    const float* __restrict__ bx, const float* __restrict__ gx,
    const float* __restrict__ bxb, const float* __restrict__ Wfc,
    const float* __restrict__ bfc, const float* __restrict__ Wo0,
    const float* __restrict__ bo0, const float* __restrict__ Wo1,
    const float* __restrict__ bo1, const float* __restrict__ Wo2,
    const float* __restrict__ bo2, float* __restrict__ out) {
  const int b = blockIdx.x;
  const int t = threadIdx.x;
  __shared__ float vbuf[80];
  __shared__ float part[128];
  __shared__ float4 r4[128];
  const int lo = lbound(seg, N_ATOMS, b);
  const int hi = lbound(seg, N_ATOMS, b + 1);
  const int col = t & 63, half = t >> 6;
  float s = 0.f;
  for (int r = lo + half; r < hi; r += 2) s += Xf[(size_t)r * 64 + col];
  part[t] = s;
  __syncthreads();
  if (t < 64) {
    vbuf[t] = (part[t] + part[t + 64]) / fmaxf((float)(hi - lo), 1.f);
  } else if (t < 80) {
    const int e = t - 64;
    float a = bx[e];
#pragma unroll
    for (int k = 0; k < 8; ++k) a += EF[b * 8 + k] * Wx[k * 16 + e];
    a = a * (gx[e] * rsqrtf(1.f + EPSBN)) + bxb[e];
    vbuf[t] = sp(a);
  }
  __syncthreads();
  float h = bfc[t];
#pragma unroll
  for (int k = 0; k < 80; ++k) h += vbuf[k] * Wfc[k * 128 + t];
  h = sp(h);
  r4[t] = make_float4(h * Wo0[t], h * Wo1[2 * t], h * Wo1[2 * t + 1],
                      h * Wo2[t]);
  __syncthreads();
  for (int st2 = 64; st2 > 0; st2 >>= 1) {
    if (t < st2) {
      float4 a = r4[t], c = r4[t + st2];
      r4[t] = make_float4(a.x + c.x, a.y + c.y, a.z + c.z, a.w + c.w);
    }
    __syncthreads();
  }
  if (t == 0) {
    float4 r = r4[0];
    out[b] = r.x + bo0[0];
    float z0 = r.y + bo1[0], z1 = r.z + bo1[1];
    float mx = fmaxf(z0, z1);
    float lse = mx + __logf(__expf(z0 - mx) + __expf(z1 - mx));
    out[B_CRYS + 2 * b] = z0 - lse;
    out[B_CRYS + 2 * b + 1] = z1 - lse;
    out[3 * B_CRYS + b] = r.w + bo2[0];
  }
}

// ---------------------------------------------------------------------------
extern "C" void kernel_launch(void* const* d_in, const int* in_sizes, int n_in,
                              void* d_out, int out_size, void* d_ws,
                              size_t ws_size, hipStream_t stream) {
  const float* atom_fea = (const float*)d_in[0];
  const float* nbr_fea  = (const float*)d_in[1];
  const int*   nbr_idx  = (const int*)d_in[2];
  const int*   seg      = (const int*)d_in[3];
  const float* extra    = (const float*)d_in[4];
  const float* W_embed  = (const float*)d_in[5];
  const float* b_embed  = (const float*)d_in[6];
  const float* conv_W   = (const float*)d_in[7];
  const float* conv_b   = (const float*)d_in[8];
  const float* bn1_g    = (const float*)d_in[9];
  const float* bn1_b    = (const float*)d_in[10];
  const float* bn2_g    = (const float*)d_in[11];
  const float* bn2_b    = (const float*)d_in[12];
  const float* W_extra  = (const float*)d_in[13];
  const float* b_extra  = (const float*)d_in[14];
  const float* bnx_g    = (const float*)d_in[15];
  const float* bnx_b    = (const float*)d_in[16];
  const float* W_fc     = (const float*)d_in[17];
  const float* b_fc     = (const float*)d_in[18];
  const float* W_out0   = (const float*)d_in[19];
  const float* b_out0   = (const float*)d_in[20];
  const float* W_out1   = (const float*)d_in[21];
  const float* b_out1   = (const float*)d_in[22];
  const float* W_out2   = (const float*)d_in[23];
  const float* b_out2   = (const float*)d_in[24];
  float* out = (float*)d_out;

  // workspace: x [60000*64] | yself [60000*128] | ynbr [60000*128] = 76.8 MB
  float* x  = (float*)d_ws;
  float* ys = x + (size_t)N_ATOMS * 64;
  float* yn = ys + (size_t)N_ATOMS * 128;

  hipLaunchKernelGGL(k_embed, dim3(512), dim3(256), 0, stream, atom_fea,
                     W_embed, b_embed, x);
  for (int i = 0; i < 3; ++i) {
    const float* Wc = conv_W + (size_t)i * 169 * 128;
    hipLaunchKernelGGL(k_lin, dim3(512, 2), dim3(256), 0, stream, x, Wc,
                       conv_b + i * 128, bn1_g + i * 128, bn1_b + i * 128, ys,
                       yn);
    hipLaunchKernelGGL(k_conv, dim3(1024), dim3(256), 0, stream, x, ys, yn,
                       nbr_fea, nbr_idx, Wc, bn1_g + i * 128, bn2_g + i * 64,
                       bn2_b + i * 64);
  }
  hipLaunchKernelGGL(k_head, dim3(B_CRYS), dim3(128), 0, stream, x, seg, extra,
                     W_extra, b_extra, bnx_g, bnx_b, W_fc, b_fc, W_out0, b_out0,
                     W_out1, b_out1, W_out2, b_out2, out);
}

// Round 2
// 1111.484 us; speedup vs baseline: 1.7924x; 1.7924x over previous
//
#include <hip/hip_runtime.h>
#include <math.h>
#include <stdint.h>

#define N_ATOMS 60000
#define M_NBR   12
#define NBF     41
#define B_CRYS  2048
#define EPSBN   1e-5f
#define CHUNK   10000   // atoms per E chunk: E = 120000 rows x 256B = 30.72 MB

typedef __attribute__((ext_vector_type(8))) short bf8;
typedef __attribute__((ext_vector_type(4))) float f32x4;
#define MFMA_B16(a, b, c) __builtin_amdgcn_mfma_f32_16x16x32_bf16(a, b, c, 0, 0, 0)

__device__ __forceinline__ short f2bf(float f) {
  uint32_t u = __builtin_bit_cast(uint32_t, f);
  u += 0x7FFFu + ((u >> 16) & 1u);
  return (short)(u >> 16);
}
__device__ __forceinline__ float lo16(uint32_t u) {
  return __builtin_bit_cast(float, u << 16);
}
__device__ __forceinline__ float hi16(uint32_t u) {
  return __builtin_bit_cast(float, u & 0xFFFF0000u);
}
__device__ __forceinline__ float sp(float x) {
  return (x > 15.f) ? x : __logf(1.f + __expf(x));
}
__device__ __forceinline__ float sig(float x) {
  return 1.f / (1.f + __expf(-x));
}

// ---------------------------------------------------------------------------
// X[60000,64] = atom_fea[60000,92] @ W_embed[92,64] + b_embed   (MFMA bf16)
// K padded 92->96 (3 k-steps of 32). Output fp32.
// ---------------------------------------------------------------------------
__global__ __launch_bounds__(256) void k_embed2(
    const float* __restrict__ A, const float* __restrict__ W,
    const float* __restrict__ bias, float* __restrict__ X) {
  const int lane = threadIdx.x & 63, wv = threadIdx.x >> 6;
  const int quad = lane >> 4, l15 = lane & 15;
  const int gw = blockIdx.x * 4 + wv, nw = gridDim.x * 4;
  bf8 Bf[3][4];
  float bs[4];
#pragma unroll
  for (int ct = 0; ct < 4; ++ct) {
    const int col = ct * 16 + l15;
    bs[ct] = bias[col];
#pragma unroll
    for (int ks = 0; ks < 3; ++ks) {
      bf8 b;
#pragma unroll
      for (int i = 0; i < 8; ++i) {
        const int k = ks * 32 + quad * 8 + i;
        b[i] = (k < 92) ? f2bf(W[k * 64 + col]) : (short)0;
      }
      Bf[ks][ct] = b;
    }
  }
  for (int rt = gw; rt < 3750; rt += nw) {
    const int rbase = rt * 16;
    const float* ar = A + (size_t)(rbase + l15) * 92;
    const float4 p0 = *(const float4*)(ar + quad * 8);
    const float4 p1 = *(const float4*)(ar + quad * 8 + 4);
    const float4 p2 = *(const float4*)(ar + 32 + quad * 8);
    const float4 p3 = *(const float4*)(ar + 32 + quad * 8 + 4);
    bf8 A0, A1, A2;
    A0[0] = f2bf(p0.x); A0[1] = f2bf(p0.y); A0[2] = f2bf(p0.z); A0[3] = f2bf(p0.w);
    A0[4] = f2bf(p1.x); A0[5] = f2bf(p1.y); A0[6] = f2bf(p1.z); A0[7] = f2bf(p1.w);
    A1[0] = f2bf(p2.x); A1[1] = f2bf(p2.y); A1[2] = f2bf(p2.z); A1[3] = f2bf(p2.w);
    A1[4] = f2bf(p3.x); A1[5] = f2bf(p3.y); A1[6] = f2bf(p3.z); A1[7] = f2bf(p3.w);
#pragma unroll
    for (int i = 0; i < 8; ++i) {
      const int k = 64 + quad * 8 + i;
      A2[i] = (k < 92) ? f2bf(ar[k]) : (short)0;
    }
    const f32x4 z = {0.f, 0.f, 0.f, 0.f};
    f32x4 acc[4];
#pragma unroll
    for (int ct = 0; ct < 4; ++ct) {
      acc[ct] = MFMA_B16(A0, Bf[0][ct], z);
      acc[ct] = MFMA_B16(A1, Bf[1][ct], acc[ct]);
      acc[ct] = MFMA_B16(A2, Bf[2][ct], acc[ct]);
    }
#pragma unroll
    for (int ct = 0; ct < 4; ++ct)
#pragma unroll
      for (int r = 0; r < 4; ++r)
        X[(size_t)(rbase + quad * 4 + r) * 64 + ct * 16 + l15] =
            acc[ct][r] + bs[ct];
  }
}

// ---------------------------------------------------------------------------
// Y[60000, 256 bf16] = X @ [W_self | W_nbr], bn1-folded, column-PAIRED:
//   Y[n][2c]   = (X[n]@W[half*64:.. , c])*s1[c]      (+bias for self half)
//   Y[n][2c+1] = same for original col c+64
// half = Ys (cols 0..127) or Yn (cols 128..255), one half per wave.
// ---------------------------------------------------------------------------
__global__ __launch_bounds__(256) void k_ygemm(
    const float* __restrict__ X, const float* __restrict__ Wc,
    const float* __restrict__ bc, const float* __restrict__ g1,
    const float* __restrict__ b1, unsigned short* __restrict__ Y) {
  const int lane = threadIdx.x & 63, wv = threadIdx.x >> 6;
  const int quad = lane >> 4, l15 = lane & 15;
  const int gw = blockIdx.x * 4 + wv, nw = gridDim.x * 4;
  const int half = gw & 1;
  const float inv = rsqrtf(1.f + EPSBN);
  bf8 Bf[2][8];
  float bs[8];
#pragma unroll
  for (int ct = 0; ct < 8; ++ct) {
    const int j = ct * 16 + l15;
    const int oc = (j & 1) ? (j >> 1) + 64 : (j >> 1);
    const float s = g1[oc] * inv;
    bs[ct] = half ? 0.f : (bc[oc] * s + b1[oc]);
#pragma unroll
    for (int ks = 0; ks < 2; ++ks) {
      bf8 b;
#pragma unroll
      for (int i = 0; i < 8; ++i) {
        const int k = ks * 32 + quad * 8 + i;
        b[i] = f2bf(Wc[(half * 64 + k) * 128 + oc] * s);
      }
      Bf[ks][ct] = b;
    }
  }
  for (int rt = (gw >> 1); rt < 3750; rt += (nw >> 1)) {
    const int rbase = rt * 16;
    const float* xr = X + (size_t)(rbase + l15) * 64;
    const float4 p0 = *(const float4*)(xr + quad * 8);
    const float4 p1 = *(const float4*)(xr + quad * 8 + 4);
    const float4 p2 = *(const float4*)(xr + 32 + quad * 8);
    const float4 p3 = *(const float4*)(xr + 32 + quad * 8 + 4);
    bf8 A0, A1;
    A0[0] = f2bf(p0.x); A0[1] = f2bf(p0.y); A0[2] = f2bf(p0.z); A0[3] = f2bf(p0.w);
    A0[4] = f2bf(p1.x); A0[5] = f2bf(p1.y); A0[6] = f2bf(p1.z); A0[7] = f2bf(p1.w);
    A1[0] = f2bf(p2.x); A1[1] = f2bf(p2.y); A1[2] = f2bf(p2.z); A1[3] = f2bf(p2.w);
    A1[4] = f2bf(p3.x); A1[5] = f2bf(p3.y); A1[6] = f2bf(p3.z); A1[7] = f2bf(p3.w);
    const f32x4 z = {0.f, 0.f, 0.f, 0.f};
    f32x4 acc[8];
#pragma unroll
    for (int ct = 0; ct < 8; ++ct) {
      acc[ct] = MFMA_B16(A0, Bf[0][ct], z);
      acc[ct] = MFMA_B16(A1, Bf[1][ct], acc[ct]);
    }
#pragma unroll
    for (int ct = 0; ct < 8; ++ct)
#pragma unroll
      for (int r = 0; r < 4; ++r)
        Y[(size_t)(rbase + quad * 4 + r) * 256 + half * 128 + ct * 16 + l15] =
            (unsigned short)f2bf(acc[ct][r] + bs[ct]);
  }
}

// ---------------------------------------------------------------------------
// E[chunk rows, 128 bf16] = nbr_fea[row0+r, :41] @ W_edge*s1, column-paired.
// K padded 41->64 (2 k-steps). Rows are edges r = n*12+m (chunk-local).
// ---------------------------------------------------------------------------
__global__ __launch_bounds__(256) void k_egemm(
    const float* __restrict__ NF, const float* __restrict__ Wc,
    const float* __restrict__ g1, unsigned short* __restrict__ E, int row0,
    int ntiles) {
  const int lane = threadIdx.x & 63, wv = threadIdx.x >> 6;
  const int quad = lane >> 4, l15 = lane & 15;
  const int gw = blockIdx.x * 4 + wv, nw = gridDim.x * 4;
  const float inv = rsqrtf(1.f + EPSBN);
  bf8 Bf[2][8];
#pragma unroll
  for (int ct = 0; ct < 8; ++ct) {
    const int j = ct * 16 + l15;
    const int oc = (j & 1) ? (j >> 1) + 64 : (j >> 1);
    const float s = g1[oc] * inv;
#pragma unroll
    for (int ks = 0; ks < 2; ++ks) {
      bf8 b;
#pragma unroll
      for (int i = 0; i < 8; ++i) {
        const int k = ks * 32 + quad * 8 + i;
        b[i] = (k < NBF) ? f2bf(Wc[(128 + k) * 128 + oc] * s) : (short)0;
      }
      Bf[ks][ct] = b;
    }
  }
  for (int rt = gw; rt < ntiles; rt += nw) {
    const int rbase = rt * 16;
    const float* ar = NF + (size_t)(row0 + rbase + l15) * NBF;
    bf8 A0, A1;
#pragma unroll
    for (int i = 0; i < 8; ++i) A0[i] = f2bf(ar[quad * 8 + i]);
#pragma unroll
    for (int i = 0; i < 8; ++i) {
      const int k = 32 + quad * 8 + i;
      A1[i] = (k < NBF) ? f2bf(ar[k]) : (short)0;
    }
    const f32x4 z = {0.f, 0.f, 0.f, 0.f};
    f32x4 acc[8];
#pragma unroll
    for (int ct = 0; ct < 8; ++ct) {
      acc[ct] = MFMA_B16(A0, Bf[0][ct], z);
      acc[ct] = MFMA_B16(A1, Bf[1][ct], acc[ct]);
    }
#pragma unroll
    for (int ct = 0; ct < 8; ++ct)
#pragma unroll
      for (int r = 0; r < 4; ++r)
        E[(size_t)(rbase + quad * 4 + r) * 128 + ct * 16 + l15] =
            (unsigned short)f2bf(acc[ct][r]);
  }
}

// ---------------------------------------------------------------------------
// Conv tail: gate = Ys[n] + Yn[idx] + E[r] (all bf16 paired -> one uint/lane),
// acc = sum_m sig(flt)*sp(core); X = sp(X + acc*s2 + b2). In-place on X.
// ---------------------------------------------------------------------------
__global__ __launch_bounds__(256) void k_conv2(
    float* __restrict__ X, const unsigned int* __restrict__ Yu,
    const unsigned int* __restrict__ Eu, const int* __restrict__ IDX,
    const float* __restrict__ g2, const float* __restrict__ b2, int n0,
    int natoms) {
  const int t = threadIdx.x & 63, wv = threadIdx.x >> 6;
  const int gw = blockIdx.x * 4 + wv, nw = gridDim.x * 4;
  const float inv = rsqrtf(1.f + EPSBN);
  const float s2 = g2[t] * inv, o2 = b2[t];
  for (int a = gw; a < natoms; a += nw) {
    const int n = n0 + a;
    const uint32_t ysu = Yu[(size_t)n * 128 + t];
    const int4* ir = (const int4*)(IDX + (size_t)n * 12);
    const int4 ia = ir[0], ib = ir[1], ic = ir[2];
    const int jj[12] = {ia.x, ia.y, ia.z, ia.w, ib.x, ib.y,
                        ib.z, ib.w, ic.x, ic.y, ic.z, ic.w};
    uint32_t eu[12], ynu[12];
#pragma unroll
    for (int m = 0; m < 12; ++m) {
      eu[m] = Eu[(size_t)(a * 12 + m) * 64 + t];
      ynu[m] = Yu[(size_t)jj[m] * 128 + 64 + t];
    }
    const float ysf = lo16(ysu), ysc = hi16(ysu);
    float acc = 0.f;
#pragma unroll
    for (int m = 0; m < 12; ++m) {
      const float flt = ysf + lo16(ynu[m]) + lo16(eu[m]);
      const float core = ysc + hi16(ynu[m]) + hi16(eu[m]);
      acc += sig(flt) * sp(core);
    }
    const float xv = X[(size_t)n * 64 + t];
    X[(size_t)n * 64 + t] = sp(xv + acc * s2 + o2);
  }
}

// ---------------------------------------------------------------------------
// Pool + extra embedding + FC + 3 heads (unchanged from R1, verified).
// ---------------------------------------------------------------------------
__device__ __forceinline__ int lbound(const int* __restrict__ a, int n, int v) {
  int lo = 0, hi = n;
  while (lo < hi) {
    int mid = (lo + hi) >> 1;
    if (a[mid] < v) lo = mid + 1; else hi = mid;
  }
  return lo;
}

__global__ __launch_bounds__(128) void k_head(
    const float* __restrict__ Xf, const int* __restrict__ seg,
    const float* __restrict__ EF, const float* __restrict__ Wx,
    const float* __restrict__ bx, const float* __restrict__ gx,
    const float* __restrict__ bxb, const float* __restrict__ Wfc,
    const float* __restrict__ bfc, const float* __restrict__ Wo0,
    const float* __restrict__ bo0, const float* __restrict__ Wo1,
    const float* __restrict__ bo1, const float* __restrict__ Wo2,
    const float* __restrict__ bo2, float* __restrict__ out) {
  const int b = blockIdx.x;
  const int t = threadIdx.x;
  __shared__ float vbuf[80];
  __shared__ float part[128];
  __shared__ float4 r4[128];
  const int lo = lbound(seg, N_ATOMS, b);
  const int hi = lbound(seg, N_ATOMS, b + 1);
  const int col = t & 63, half = t >> 6;
  float s = 0.f;
  for (int r = lo + half; r < hi; r += 2) s += Xf[(size_t)r * 64 + col];
  part[t] = s;
  __syncthreads();
  if (t < 64) {
    vbuf[t] = (part[t] + part[t + 64]) / fmaxf((float)(hi - lo), 1.f);
  } else if (t < 80) {
    const int e = t - 64;
    float a = bx[e];
#pragma unroll
    for (int k = 0; k < 8; ++k) a += EF[b * 8 + k] * Wx[k * 16 + e];
    a = a * (gx[e] * rsqrtf(1.f + EPSBN)) + bxb[e];
    vbuf[t] = sp(a);
  }
  __syncthreads();
  float h = bfc[t];
#pragma unroll
  for (int k = 0; k < 80; ++k) h += vbuf[k] * Wfc[k * 128 + t];
  h = sp(h);
  r4[t] = make_float4(h * Wo0[t], h * Wo1[2 * t], h * Wo1[2 * t + 1],
                      h * Wo2[t]);
  __syncthreads();
  for (int st2 = 64; st2 > 0; st2 >>= 1) {
    if (t < st2) {
      float4 a = r4[t], c = r4[t + st2];
      r4[t] = make_float4(a.x + c.x, a.y + c.y, a.z + c.z, a.w + c.w);
    }
    __syncthreads();
  }
  if (t == 0) {
    float4 r = r4[0];
    out[b] = r.x + bo0[0];
    float z0 = r.y + bo1[0], z1 = r.z + bo1[1];
    float mx = fmaxf(z0, z1);
    float lse = mx + __logf(__expf(z0 - mx) + __expf(z1 - mx));
    out[B_CRYS + 2 * b] = z0 - lse;
    out[B_CRYS + 2 * b + 1] = z1 - lse;
    out[3 * B_CRYS + b] = r.w + bo2[0];
  }
}

// ---------------------------------------------------------------------------
extern "C" void kernel_launch(void* const* d_in, const int* in_sizes, int n_in,
                              void* d_out, int out_size, void* d_ws,
                              size_t ws_size, hipStream_t stream) {
  const float* atom_fea = (const float*)d_in[0];
  const float* nbr_fea  = (const float*)d_in[1];
  const int*   nbr_idx  = (const int*)d_in[2];
  const int*   seg      = (const int*)d_in[3];
  const float* extra    = (const float*)d_in[4];
  const float* W_embed  = (const float*)d_in[5];
  const float* b_embed  = (const float*)d_in[6];
  const float* conv_W   = (const float*)d_in[7];
  const float* conv_b   = (const float*)d_in[8];
  const float* bn1_g    = (const float*)d_in[9];
  const float* bn1_b    = (const float*)d_in[10];
  const float* bn2_g    = (const float*)d_in[11];
  const float* bn2_b    = (const float*)d_in[12];
  const float* W_extra  = (const float*)d_in[13];
  const float* b_extra  = (const float*)d_in[14];
  const float* bnx_g    = (const float*)d_in[15];
  const float* bnx_b    = (const float*)d_in[16];
  const float* W_fc     = (const float*)d_in[17];
  const float* b_fc     = (const float*)d_in[18];
  const float* W_out0   = (const float*)d_in[19];
  const float* b_out0   = (const float*)d_in[20];
  const float* W_out1   = (const float*)d_in[21];
  const float* b_out1   = (const float*)d_in[22];
  const float* W_out2   = (const float*)d_in[23];
  const float* b_out2   = (const float*)d_in[24];
  float* out = (float*)d_out;

  // ws: X f32 [60000*64] | Y bf16 [60000*256] | E bf16 [120000*128]  = 76.8 MB
  float* x = (float*)d_ws;
  unsigned short* Y = (unsigned short*)(x + (size_t)N_ATOMS * 64);
  unsigned short* E = Y + (size_t)N_ATOMS * 256;

  hipLaunchKernelGGL(k_embed2, dim3(256), dim3(256), 0, stream, atom_fea,
                     W_embed, b_embed, x);
  for (int i = 0; i < 3; ++i) {
    const float* Wc = conv_W + (size_t)i * 169 * 128;
    hipLaunchKernelGGL(k_ygemm, dim3(256), dim3(256), 0, stream, x, Wc,
                       conv_b + i * 128, bn1_g + i * 128, bn1_b + i * 128, Y);
    for (int c = 0; c < N_ATOMS / CHUNK; ++c) {
      hipLaunchKernelGGL(k_egemm, dim3(512), dim3(256), 0, stream, nbr_fea, Wc,
                         bn1_g + i * 128, E, c * CHUNK * 12,
                         (CHUNK * 12) / 16);
      hipLaunchKernelGGL(k_conv2, dim3(512), dim3(256), 0, stream, x,
                         (const unsigned int*)Y, (const unsigned int*)E,
                         nbr_idx, bn2_g + i * 64, bn2_b + i * 64, c * CHUNK,
                         CHUNK);
    }
  }
  hipLaunchKernelGGL(k_head, dim3(B_CRYS), dim3(128), 0, stream, x, seg, extra,
                     W_extra, b_extra, bnx_g, bnx_b, W_fc, b_fc, W_out0, b_out0,
                     W_out1, b_out1, W_out2, b_out2, out);
}

// Round 3
// 897.984 us; speedup vs baseline: 2.2186x; 1.2378x over previous
//
#include <hip/hip_runtime.h>
#include <math.h>
#include <stdint.h>

#define N_ATOMS 60000
#define M_NBR   12
#define NBF     41
#define B_CRYS  2048
#define EPSBN   1e-5f
#define GA      16            // atoms per block in fused kernel
#define GROUPS  (N_ATOMS / GA)   // 3750

typedef __attribute__((ext_vector_type(8))) short bf8;
typedef __attribute__((ext_vector_type(4))) float f32x4;
#define MFMA_B16(a, b, c) __builtin_amdgcn_mfma_f32_16x16x32_bf16(a, b, c, 0, 0, 0)

__device__ __forceinline__ short f2bf(float f) {
  uint32_t u = __builtin_bit_cast(uint32_t, f);
  u += 0x7FFFu + ((u >> 16) & 1u);
  return (short)(u >> 16);
}
__device__ __forceinline__ float lo16(uint32_t u) {
  return __builtin_bit_cast(float, u << 16);
}
__device__ __forceinline__ float hi16(uint32_t u) {
  return __builtin_bit_cast(float, u & 0xFFFF0000u);
}
__device__ __forceinline__ float sp(float x) {
  return (x > 15.f) ? x : __logf(1.f + __expf(x));
}
__device__ __forceinline__ float sig(float x) {
  return 1.f / (1.f + __expf(-x));
}

// ---------------------------------------------------------------------------
// X[60000,64] = atom_fea[60000,92] @ W_embed[92,64] + b_embed   (MFMA bf16)
// ---------------------------------------------------------------------------
__global__ __launch_bounds__(256) void k_embed2(
    const float* __restrict__ A, const float* __restrict__ W,
    const float* __restrict__ bias, float* __restrict__ X) {
  const int lane = threadIdx.x & 63, wv = threadIdx.x >> 6;
  const int quad = lane >> 4, l15 = lane & 15;
  const int gw = blockIdx.x * 4 + wv, nw = gridDim.x * 4;
  bf8 Bf[3][4];
  float bs[4];
#pragma unroll
  for (int ct = 0; ct < 4; ++ct) {
    const int col = ct * 16 + l15;
    bs[ct] = bias[col];
#pragma unroll
    for (int ks = 0; ks < 3; ++ks) {
      bf8 b;
#pragma unroll
      for (int i = 0; i < 8; ++i) {
        const int k = ks * 32 + quad * 8 + i;
        b[i] = (k < 92) ? f2bf(W[k * 64 + col]) : (short)0;
      }
      Bf[ks][ct] = b;
    }
  }
  for (int rt = gw; rt < 3750; rt += nw) {
    const int rbase = rt * 16;
    const float* ar = A + (size_t)(rbase + l15) * 92;
    const float4 p0 = *(const float4*)(ar + quad * 8);
    const float4 p1 = *(const float4*)(ar + quad * 8 + 4);
    const float4 p2 = *(const float4*)(ar + 32 + quad * 8);
    const float4 p3 = *(const float4*)(ar + 32 + quad * 8 + 4);
    bf8 A0, A1, A2;
    A0[0] = f2bf(p0.x); A0[1] = f2bf(p0.y); A0[2] = f2bf(p0.z); A0[3] = f2bf(p0.w);
    A0[4] = f2bf(p1.x); A0[5] = f2bf(p1.y); A0[6] = f2bf(p1.z); A0[7] = f2bf(p1.w);
    A1[0] = f2bf(p2.x); A1[1] = f2bf(p2.y); A1[2] = f2bf(p2.z); A1[3] = f2bf(p2.w);
    A1[4] = f2bf(p3.x); A1[5] = f2bf(p3.y); A1[6] = f2bf(p3.z); A1[7] = f2bf(p3.w);
#pragma unroll
    for (int i = 0; i < 8; ++i) {
      const int k = 64 + quad * 8 + i;
      A2[i] = (k < 92) ? f2bf(ar[k]) : (short)0;
    }
    const f32x4 z = {0.f, 0.f, 0.f, 0.f};
    f32x4 acc[4];
#pragma unroll
    for (int ct = 0; ct < 4; ++ct) {
      acc[ct] = MFMA_B16(A0, Bf[0][ct], z);
      acc[ct] = MFMA_B16(A1, Bf[1][ct], acc[ct]);
      acc[ct] = MFMA_B16(A2, Bf[2][ct], acc[ct]);
    }
#pragma unroll
    for (int ct = 0; ct < 4; ++ct)
#pragma unroll
      for (int r = 0; r < 4; ++r)
        X[(size_t)(rbase + quad * 4 + r) * 64 + ct * 16 + l15] =
            acc[ct][r] + bs[ct];
  }
}

// ---------------------------------------------------------------------------
// Y[60000, 256 bf16] = X @ [W_self | W_nbr], bn1-folded, column-PAIRED:
// word c of row n: lo = flt col c, hi = core col c. Halves: self then nbr.
// ---------------------------------------------------------------------------
__global__ __launch_bounds__(256) void k_ygemm(
    const float* __restrict__ X, const float* __restrict__ Wc,
    const float* __restrict__ bc, const float* __restrict__ g1,
    const float* __restrict__ b1, unsigned short* __restrict__ Y) {
  const int lane = threadIdx.x & 63, wv = threadIdx.x >> 6;
  const int quad = lane >> 4, l15 = lane & 15;
  const int gw = blockIdx.x * 4 + wv, nw = gridDim.x * 4;
  const int half = gw & 1;
  const float inv = rsqrtf(1.f + EPSBN);
  bf8 Bf[2][8];
  float bs[8];
#pragma unroll
  for (int ct = 0; ct < 8; ++ct) {
    const int j = ct * 16 + l15;
    const int oc = (j & 1) ? (j >> 1) + 64 : (j >> 1);
    const float s = g1[oc] * inv;
    bs[ct] = half ? 0.f : (bc[oc] * s + b1[oc]);
#pragma unroll
    for (int ks = 0; ks < 2; ++ks) {
      bf8 b;
#pragma unroll
      for (int i = 0; i < 8; ++i) {
        const int k = ks * 32 + quad * 8 + i;
        b[i] = f2bf(Wc[(half * 64 + k) * 128 + oc] * s);
      }
      Bf[ks][ct] = b;
    }
  }
  for (int rt = (gw >> 1); rt < 3750; rt += (nw >> 1)) {
    const int rbase = rt * 16;
    const float* xr = X + (size_t)(rbase + l15) * 64;
    const float4 p0 = *(const float4*)(xr + quad * 8);
    const float4 p1 = *(const float4*)(xr + quad * 8 + 4);
    const float4 p2 = *(const float4*)(xr + 32 + quad * 8);
    const float4 p3 = *(const float4*)(xr + 32 + quad * 8 + 4);
    bf8 A0, A1;
    A0[0] = f2bf(p0.x); A0[1] = f2bf(p0.y); A0[2] = f2bf(p0.z); A0[3] = f2bf(p0.w);
    A0[4] = f2bf(p1.x); A0[5] = f2bf(p1.y); A0[6] = f2bf(p1.z); A0[7] = f2bf(p1.w);
    A1[0] = f2bf(p2.x); A1[1] = f2bf(p2.y); A1[2] = f2bf(p2.z); A1[3] = f2bf(p2.w);
    A1[4] = f2bf(p3.x); A1[5] = f2bf(p3.y); A1[6] = f2bf(p3.z); A1[7] = f2bf(p3.w);
    const f32x4 z = {0.f, 0.f, 0.f, 0.f};
    f32x4 acc[8];
#pragma unroll
    for (int ct = 0; ct < 8; ++ct) {
      acc[ct] = MFMA_B16(A0, Bf[0][ct], z);
      acc[ct] = MFMA_B16(A1, Bf[1][ct], acc[ct]);
    }
#pragma unroll
    for (int ct = 0; ct < 8; ++ct)
#pragma unroll
      for (int r = 0; r < 4; ++r)
        Y[(size_t)(rbase + quad * 4 + r) * 256 + half * 128 + ct * 16 + l15] =
            (unsigned short)f2bf(acc[ct][r] + bs[ct]);
  }
}

// ---------------------------------------------------------------------------
// FUSED edge-GEMM + conv tail. One block = 16 atoms = 192 edge rows.
// Phase 1: E-tile = nbr_fea @ W_edge*s1 (MFMA) -> LDS bf16 pairs,
//          col-swizzled: word index = row*64 + ((c+row)&63).
// Phase 2: gate = Ys[n] + Yn[idx] + E_lds; acc = sum_m sig*sp;
//          X[n] = sp(X[n] + acc*s2 + b2)   (in-place).
// ---------------------------------------------------------------------------
__global__ __launch_bounds__(256) void k_fused(
    float* __restrict__ X, const unsigned int* __restrict__ Yu,
    const float* __restrict__ NF, const int* __restrict__ IDX,
    const float* __restrict__ Wc, const float* __restrict__ g1,
    const float* __restrict__ g2, const float* __restrict__ b2) {
  __shared__ unsigned int eb32[192 * 64];  // 48 KB
  unsigned short* eb16 = (unsigned short*)eb32;
  const int lane = threadIdx.x & 63, wv = threadIdx.x >> 6;
  const int quad = lane >> 4, l15 = lane & 15;
  const int g = blockIdx.x;
  const float inv = rsqrtf(1.f + EPSBN);

  // --- B fragments (bn1-folded edge weights), paired cols ---
  bf8 Bf[2][8];
#pragma unroll
  for (int ct = 0; ct < 8; ++ct) {
    const int j = ct * 16 + l15;
    const int oc = (j & 1) ? (j >> 1) + 64 : (j >> 1);
    const float s = g1[oc] * inv;
#pragma unroll
    for (int ks = 0; ks < 2; ++ks) {
      bf8 b;
#pragma unroll
      for (int i = 0; i < 8; ++i) {
        const int k = ks * 32 + quad * 8 + i;
        b[i] = (k < NBF) ? f2bf(Wc[(128 + k) * 128 + oc] * s) : (short)0;
      }
      Bf[ks][ct] = b;
    }
  }

  // --- Phase 1: 12 row-tiles of 16 edges, 3 per wave ---
#pragma unroll
  for (int rti = 0; rti < 3; ++rti) {
    const int rt = wv + rti * 4;
    const int rbase = rt * 16;  // local edge row base (0..176)
    const float* ar = NF + (size_t)(g * 192 + rbase + l15) * NBF;
    bf8 A0, A1;
#pragma unroll
    for (int i = 0; i < 8; ++i) A0[i] = f2bf(ar[quad * 8 + i]);
#pragma unroll
    for (int i = 0; i < 8; ++i) {
      const int k = 32 + quad * 8 + i;
      A1[i] = (k < NBF) ? f2bf(ar[k]) : (short)0;
    }
    const f32x4 z = {0.f, 0.f, 0.f, 0.f};
#pragma unroll
    for (int ct = 0; ct < 8; ++ct) {
      f32x4 acc = MFMA_B16(A0, Bf[0][ct], z);
      acc = MFMA_B16(A1, Bf[1][ct], acc);
      const int j = ct * 16 + l15;
      const int c = j >> 1, h = j & 1;
#pragma unroll
      for (int r = 0; r < 4; ++r) {
        const int row = rbase + quad * 4 + r;
        const int col = (c + row) & 63;
        eb16[row * 128 + col * 2 + h] = (unsigned short)f2bf(acc[r]);
      }
    }
  }
  __syncthreads();

  // --- Phase 2: conv tail, 4 atoms per wave ---
  const int t = lane;
  const float s2 = g2[t] * inv, o2 = b2[t];
#pragma unroll
  for (int al = 0; al < 4; ++al) {
    const int a_local = wv * 4 + al;
    const int n = g * GA + a_local;
    const uint32_t ysu = Yu[(size_t)n * 128 + t];
    const int4* ir = (const int4*)(IDX + (size_t)n * 12);
    const int4 ia = ir[0], ib = ir[1], ic = ir[2];
    const int jj[12] = {ia.x, ia.y, ia.z, ia.w, ib.x, ib.y,
                        ib.z, ib.w, ic.x, ic.y, ic.z, ic.w};
    uint32_t eu[12], ynu[12];
#pragma unroll
    for (int m = 0; m < 12; ++m) {
      const int row = a_local * 12 + m;
      eu[m] = eb32[row * 64 + ((t + row) & 63)];
      ynu[m] = Yu[(size_t)jj[m] * 128 + 64 + t];
    }
    const float ysf = lo16(ysu), ysc = hi16(ysu);
    float acc = 0.f;
#pragma unroll
    for (int m = 0; m < 12; ++m) {
      const float flt = ysf + lo16(ynu[m]) + lo16(eu[m]);
      const float core = ysc + hi16(ynu[m]) + hi16(eu[m]);
      acc += sig(flt) * sp(core);
    }
    const float xv = X[(size_t)n * 64 + t];
    X[(size_t)n * 64 + t] = sp(xv + acc * s2 + o2);
  }
}

// ---------------------------------------------------------------------------
// Pool + extra embedding + FC + 3 heads.
// ---------------------------------------------------------------------------
__device__ __forceinline__ int lbound(const int* __restrict__ a, int n, int v) {
  int lo = 0, hi = n;
  while (lo < hi) {
    int mid = (lo + hi) >> 1;
    if (a[mid] < v) lo = mid + 1; else hi = mid;
  }
  return lo;
}

__global__ __launch_bounds__(128) void k_head(
    const float* __restrict__ Xf, const int* __restrict__ seg,
    const float* __restrict__ EF, const float* __restrict__ Wx,
    const float* __restrict__ bx, const float* __restrict__ gx,
    const float* __restrict__ bxb, const float* __restrict__ Wfc,
    const float* __restrict__ bfc, const float* __restrict__ Wo0,
    const float* __restrict__ bo0, const float* __restrict__ Wo1,
    const float* __restrict__ bo1, const float* __restrict__ Wo2,
    const float* __restrict__ bo2, float* __restrict__ out) {
  const int b = blockIdx.x;
  const int t = threadIdx.x;
  __shared__ float vbuf[80];
  __shared__ float part[128];
  __shared__ float4 r4[128];
  const int lo = lbound(seg, N_ATOMS, b);
  const int hi = lbound(seg, N_ATOMS, b + 1);
  const int col = t & 63, half = t >> 6;
  float s = 0.f;
  for (int r = lo + half; r < hi; r += 2) s += Xf[(size_t)r * 64 + col];
  part[t] = s;
  __syncthreads();
  if (t < 64) {
    vbuf[t] = (part[t] + part[t + 64]) / fmaxf((float)(hi - lo), 1.f);
  } else if (t < 80) {
    const int e = t - 64;
    float a = bx[e];
#pragma unroll
    for (int k = 0; k < 8; ++k) a += EF[b * 8 + k] * Wx[k * 16 + e];
    a = a * (gx[e] * rsqrtf(1.f + EPSBN)) + bxb[e];
    vbuf[t] = sp(a);
  }
  __syncthreads();
  float h = bfc[t];
#pragma unroll
  for (int k = 0; k < 80; ++k) h += vbuf[k] * Wfc[k * 128 + t];
  h = sp(h);
  r4[t] = make_float4(h * Wo0[t], h * Wo1[2 * t], h * Wo1[2 * t + 1],
                      h * Wo2[t]);
  __syncthreads();
  for (int st2 = 64; st2 > 0; st2 >>= 1) {
    if (t < st2) {
      float4 a = r4[t], c = r4[t + st2];
      r4[t] = make_float4(a.x + c.x, a.y + c.y, a.z + c.z, a.w + c.w);
    }
    __syncthreads();
  }
  if (t == 0) {
    float4 r = r4[0];
    out[b] = r.x + bo0[0];
    float z0 = r.y + bo1[0], z1 = r.z + bo1[1];
    float mx = fmaxf(z0, z1);
    float lse = mx + __logf(__expf(z0 - mx) + __expf(z1 - mx));
    out[B_CRYS + 2 * b] = z0 - lse;
    out[B_CRYS + 2 * b + 1] = z1 - lse;
    out[3 * B_CRYS + b] = r.w + bo2[0];
  }
}

// ---------------------------------------------------------------------------
extern "C" void kernel_launch(void* const* d_in, const int* in_sizes, int n_in,
                              void* d_out, int out_size, void* d_ws,
                              size_t ws_size, hipStream_t stream) {
  const float* atom_fea = (const float*)d_in[0];
  const float* nbr_fea  = (const float*)d_in[1];
  const int*   nbr_idx  = (const int*)d_in[2];
  const int*   seg      = (const int*)d_in[3];
  const float* extra    = (const float*)d_in[4];
  const float* W_embed  = (const float*)d_in[5];
  const float* b_embed  = (const float*)d_in[6];
  const float* conv_W   = (const float*)d_in[7];
  const float* conv_b   = (const float*)d_in[8];
  const float* bn1_g    = (const float*)d_in[9];
  const float* bn1_b    = (const float*)d_in[10];
  const float* bn2_g    = (const float*)d_in[11];
  const float* bn2_b    = (const float*)d_in[12];
  const float* W_extra  = (const float*)d_in[13];
  const float* b_extra  = (const float*)d_in[14];
  const float* bnx_g    = (const float*)d_in[15];
  const float* bnx_b    = (const float*)d_in[16];
  const float* W_fc     = (const float*)d_in[17];
  const float* b_fc     = (const float*)d_in[18];
  const float* W_out0   = (const float*)d_in[19];
  const float* b_out0   = (const float*)d_in[20];
  const float* W_out1   = (const float*)d_in[21];
  const float* b_out1   = (const float*)d_in[22];
  const float* W_out2   = (const float*)d_in[23];
  const float* b_out2   = (const float*)d_in[24];
  float* out = (float*)d_out;

  // ws: X f32 [60000*64] | Y bf16 [60000*256]  = 46 MB
  float* x = (float*)d_ws;
  unsigned short* Y = (unsigned short*)(x + (size_t)N_ATOMS * 64);

  hipLaunchKernelGGL(k_embed2, dim3(256), dim3(256), 0, stream, atom_fea,
                     W_embed, b_embed, x);
  for (int i = 0; i < 3; ++i) {
    const float* Wc = conv_W + (size_t)i * 169 * 128;
    hipLaunchKernelGGL(k_ygemm, dim3(256), dim3(256), 0, stream, x, Wc,
                       conv_b + i * 128, bn1_g + i * 128, bn1_b + i * 128, Y);
    hipLaunchKernelGGL(k_fused, dim3(GROUPS), dim3(256), 0, stream, x,
                       (const unsigned int*)Y, nbr_fea, nbr_idx, Wc,
                       bn1_g + i * 128, bn2_g + i * 64, bn2_b + i * 64);
  }
  hipLaunchKernelGGL(k_head, dim3(B_CRYS), dim3(128), 0, stream, x, seg, extra,
                     W_extra, b_extra, bnx_g, bnx_b, W_fc, b_fc, W_out0, b_out0,
                     W_out1, b_out1, W_out2, b_out2, out);
}

// Round 4
// 728.730 us; speedup vs baseline: 2.7339x; 1.2323x over previous
//
#include <hip/hip_runtime.h>
#include <math.h>
#include <stdint.h>

#define N_ATOMS 60000
#define M_NBR   12
#define NBF     41
#define B_CRYS  2048
#define EPSBN   1e-5f
#define GA      8                 // atoms per fused block
#define ROWS    (GA * M_NBR)      // 96 edge rows per block
#define GRID_F  (N_ATOMS / GA)    // 7500
#define WIMG_L  24576             // shorts per layer: [edge 8192][ygS 8192][ygN 8192]

typedef __attribute__((ext_vector_type(8))) short bf8;
typedef __attribute__((ext_vector_type(4))) float f32x4;
#define MFMA_B16(a, b, c) __builtin_amdgcn_mfma_f32_16x16x32_bf16(a, b, c, 0, 0, 0)

__device__ __forceinline__ short f2bf(float f) {
  uint32_t u = __builtin_bit_cast(uint32_t, f);
  u += 0x7FFFu + ((u >> 16) & 1u);
  return (short)(u >> 16);
}
__device__ __forceinline__ float lo16(uint32_t u) {
  return __builtin_bit_cast(float, u << 16);
}
__device__ __forceinline__ float hi16(uint32_t u) {
  return __builtin_bit_cast(float, u & 0xFFFF0000u);
}
__device__ __forceinline__ float sp(float x) {
  return (x > 15.f) ? x : __logf(1.f + __expf(x));
}
__device__ __forceinline__ float sig(float x) {
  return 1.f / (1.f + __expf(-x));
}

// ---------------------------------------------------------------------------
// Weight-image prep: bn1-folded bf16 B-fragments in per-lane MFMA layout.
// Layout per layer (WIMG_L shorts): [which][frag=ct*2+ks][lane][8 shorts]
//   which 0: edge W (rows 128..168, k padded to 64)
//   which 1: self W (rows 0..63)      which 2: nbr W (rows 64..127)
// Column pairing: image col j -> orig col (j>>1) + 64*(j&1)  (flt/core pair).
// ---------------------------------------------------------------------------
__global__ __launch_bounds__(256) void k_wprep(
    const float* __restrict__ conv_W, const float* __restrict__ bn1_g,
    unsigned short* __restrict__ Wimg) {
  const int gid = blockIdx.x * 256 + threadIdx.x;
  if (gid >= 3 * WIMG_L) return;
  const int layer = gid / WIMG_L, rem = gid % WIMG_L;
  const int which = rem / 8192, r2 = rem % 8192;
  const int frag = r2 >> 9, lane = (r2 >> 3) & 63, j = r2 & 7;
  const int ct = frag >> 1, ks = frag & 1;
  const int quad = lane >> 4, l15 = lane & 15;
  const int jc = ct * 16 + l15;
  const int oc = (jc & 1) ? (jc >> 1) + 64 : (jc >> 1);
  const float s = bn1_g[layer * 128 + oc] * rsqrtf(1.f + EPSBN);
  const int k = ks * 32 + quad * 8 + j;
  const float* Wc = conv_W + (size_t)layer * 169 * 128;
  float v = 0.f;
  if (which == 0) {
    if (k < NBF) v = Wc[(128 + k) * 128 + oc] * s;
  } else if (which == 1) {
    v = Wc[k * 128 + oc] * s;
  } else {
    v = Wc[(64 + k) * 128 + oc] * s;
  }
  Wimg[gid] = (unsigned short)f2bf(v);
}

// ---------------------------------------------------------------------------
// X = atom_fea @ W_embed + b_embed (MFMA bf16); also writes bf16 shadow Xb.
// ---------------------------------------------------------------------------
__global__ __launch_bounds__(256) void k_embed2(
    const float* __restrict__ A, const float* __restrict__ W,
    const float* __restrict__ bias, float* __restrict__ X,
    unsigned short* __restrict__ Xb) {
  const int lane = threadIdx.x & 63, wv = threadIdx.x >> 6;
  const int quad = lane >> 4, l15 = lane & 15;
  const int gw = blockIdx.x * 4 + wv, nw = gridDim.x * 4;
  bf8 Bf[3][4];
  float bs[4];
#pragma unroll
  for (int ct = 0; ct < 4; ++ct) {
    const int col = ct * 16 + l15;
    bs[ct] = bias[col];
#pragma unroll
    for (int ks = 0; ks < 3; ++ks) {
      bf8 b;
#pragma unroll
      for (int i = 0; i < 8; ++i) {
        const int k = ks * 32 + quad * 8 + i;
        b[i] = (k < 92) ? f2bf(W[k * 64 + col]) : (short)0;
      }
      Bf[ks][ct] = b;
    }
  }
  for (int rt = gw; rt < 3750; rt += nw) {
    const int rbase = rt * 16;
    const float* ar = A + (size_t)(rbase + l15) * 92;
    const float4 p0 = *(const float4*)(ar + quad * 8);
    const float4 p1 = *(const float4*)(ar + quad * 8 + 4);
    const float4 p2 = *(const float4*)(ar + 32 + quad * 8);
    const float4 p3 = *(const float4*)(ar + 32 + quad * 8 + 4);
    bf8 A0, A1, A2;
    A0[0] = f2bf(p0.x); A0[1] = f2bf(p0.y); A0[2] = f2bf(p0.z); A0[3] = f2bf(p0.w);
    A0[4] = f2bf(p1.x); A0[5] = f2bf(p1.y); A0[6] = f2bf(p1.z); A0[7] = f2bf(p1.w);
    A1[0] = f2bf(p2.x); A1[1] = f2bf(p2.y); A1[2] = f2bf(p2.z); A1[3] = f2bf(p2.w);
    A1[4] = f2bf(p3.x); A1[5] = f2bf(p3.y); A1[6] = f2bf(p3.z); A1[7] = f2bf(p3.w);
#pragma unroll
    for (int i = 0; i < 8; ++i) {
      const int k = 64 + quad * 8 + i;
      A2[i] = (k < 92) ? f2bf(ar[k]) : (short)0;
    }
    const f32x4 z = {0.f, 0.f, 0.f, 0.f};
    f32x4 acc[4];
#pragma unroll
    for (int ct = 0; ct < 4; ++ct) {
      acc[ct] = MFMA_B16(A0, Bf[0][ct], z);
      acc[ct] = MFMA_B16(A1, Bf[1][ct], acc[ct]);
      acc[ct] = MFMA_B16(A2, Bf[2][ct], acc[ct]);
    }
#pragma unroll
    for (int ct = 0; ct < 4; ++ct)
#pragma unroll
      for (int r = 0; r < 4; ++r) {
        const float v = acc[ct][r] + bs[ct];
        const size_t o = (size_t)(rbase + quad * 4 + r) * 64 + ct * 16 + l15;
        X[o] = v;
        Xb[o] = (unsigned short)f2bf(v);
      }
  }
}

// ---------------------------------------------------------------------------
// Y[60000, 256 bf16] = Xb @ [W_self | W_nbr] (images), column-paired.
// ---------------------------------------------------------------------------
__global__ __launch_bounds__(256) void k_ygemm2(
    const unsigned short* __restrict__ Xb,
    const unsigned short* __restrict__ WiY, const float* __restrict__ bc,
    const float* __restrict__ g1, const float* __restrict__ b1,
    unsigned short* __restrict__ Y) {
  const int lane = threadIdx.x & 63, wv = threadIdx.x >> 6;
  const int quad = lane >> 4, l15 = lane & 15;
  const int gw = blockIdx.x * 4 + wv, nw = gridDim.x * 4;
  const int half = gw & 1;
  const float inv = rsqrtf(1.f + EPSBN);
  const unsigned short* Wb = WiY + half * 8192;
  bf8 Bf[2][8];
  float bs[8];
#pragma unroll
  for (int ct = 0; ct < 8; ++ct) {
    const int j = ct * 16 + l15;
    const int oc = (j & 1) ? (j >> 1) + 64 : (j >> 1);
    bs[ct] = half ? 0.f : (bc[oc] * (g1[oc] * inv) + b1[oc]);
#pragma unroll
    for (int ks = 0; ks < 2; ++ks)
      Bf[ks][ct] = *(const bf8*)(Wb + ((ct * 2 + ks) * 64 + lane) * 8);
  }
  for (int rt = (gw >> 1); rt < 3750; rt += (nw >> 1)) {
    const int rbase = rt * 16;
    const unsigned short* xr = Xb + (size_t)(rbase + l15) * 64;
    const bf8 A0 = *(const bf8*)(xr + quad * 8);
    const bf8 A1 = *(const bf8*)(xr + 32 + quad * 8);
    const f32x4 z = {0.f, 0.f, 0.f, 0.f};
#pragma unroll
    for (int ct = 0; ct < 8; ++ct) {
      f32x4 acc = MFMA_B16(A0, Bf[0][ct], z);
      acc = MFMA_B16(A1, Bf[1][ct], acc);
#pragma unroll
      for (int r = 0; r < 4; ++r)
        Y[(size_t)(rbase + quad * 4 + r) * 256 + half * 128 + ct * 16 + l15] =
            (unsigned short)f2bf(acc[r] + bs[ct]);
    }
  }
}

// ---------------------------------------------------------------------------
// FUSED edge-GEMM + conv tail, GA=8 atoms / 96 edge rows per block.
//   stage nbr_fea tile f32 -> LDS (coalesced float4)          | barrier
//   A-frags from LDS (2-way bank aliasing = free) + f2bf      | barrier
//   MFMA (image B-frags) -> E bf16 pairs in LDS (swizzled)    | barrier
//   gather tail: gate = Ys + Yn[idx] + E; X=sp(X+bn2(sum sig*sp)); Xb shadow.
// ---------------------------------------------------------------------------
__global__ __launch_bounds__(256, 6) void k_fused2(
    float* __restrict__ X, unsigned short* __restrict__ Xb,
    const unsigned int* __restrict__ Yu, const float* __restrict__ NF,
    const int* __restrict__ IDX, const unsigned short* __restrict__ Wi,
    const float* __restrict__ g2, const float* __restrict__ b2) {
  __shared__ __align__(16) unsigned int eb32[ROWS * 64];  // 24576 B
  unsigned short* eb16 = (unsigned short*)eb32;
  float* stage = (float*)eb32;  // first 3936 words = 96x41 f32 tile
  const int tid = threadIdx.x;
  const int lane = tid & 63, wv = tid >> 6;
  const int quad = lane >> 4, l15 = lane & 15;
  const int g = blockIdx.x;

  // B-fragments from precomputed image (16 coalesced 16B loads)
  bf8 Bf[2][8];
#pragma unroll
  for (int ct = 0; ct < 8; ++ct)
#pragma unroll
    for (int ks = 0; ks < 2; ++ks)
      Bf[ks][ct] = *(const bf8*)(Wi + ((ct * 2 + ks) * 64 + lane) * 8);

  // ---- stage 96x41 f32 tile into LDS, fully coalesced ----
  const float4* s4 = (const float4*)(NF + (size_t)g * (ROWS * NBF));
#pragma unroll
  for (int it = 0; it < 4; ++it) {
    const int w = tid + it * 256;
    if (w < (ROWS * NBF) / 4) ((float4*)stage)[w] = s4[w];
  }
  __syncthreads();

  // ---- A-fragments from LDS ----
  const int ntile = (wv < 2) ? 2 : 1;  // 6 tiles over 4 waves: 2,2,1,1
  bf8 A0a[2], A1a[2];
#pragma unroll
  for (int ti = 0; ti < 2; ++ti) {
    if (ti < ntile) {
      const int rt = wv + ti * 4;
      const float* rp = stage + (rt * 16 + l15) * NBF;
      bf8 a0, a1;
#pragma unroll
      for (int i = 0; i < 8; ++i) a0[i] = f2bf(rp[quad * 8 + i]);
      if (quad == 0) {
#pragma unroll
        for (int i = 0; i < 8; ++i) a1[i] = f2bf(rp[32 + i]);
      } else if (quad == 1) {
        a1[0] = f2bf(rp[40]);
#pragma unroll
        for (int i = 1; i < 8; ++i) a1[i] = 0;
      } else {
#pragma unroll
        for (int i = 0; i < 8; ++i) a1[i] = 0;
      }
      A0a[ti] = a0;
      A1a[ti] = a1;
    }
  }
  __syncthreads();

  // ---- MFMA + swizzled bf16-pair epilogue into LDS ----
#pragma unroll
  for (int ti = 0; ti < 2; ++ti) {
    if (ti < ntile) {
      const int rbase = (wv + ti * 4) * 16;
      const f32x4 z = {0.f, 0.f, 0.f, 0.f};
#pragma unroll
      for (int ct = 0; ct < 8; ++ct) {
        f32x4 acc = MFMA_B16(A0a[ti], Bf[0][ct], z);
        acc = MFMA_B16(A1a[ti], Bf[1][ct], acc);
        const int j = ct * 16 + l15;
        const int c = j >> 1, h = j & 1;
#pragma unroll
        for (int r = 0; r < 4; ++r) {
          const int row = rbase + quad * 4 + r;
          eb16[row * 128 + ((c + row) & 63) * 2 + h] =
              (unsigned short)f2bf(acc[r]);
        }
      }
    }
  }
  __syncthreads();

  // ---- gather tail: 2 atoms per wave ----
  const float inv = rsqrtf(1.f + EPSBN);
  const float s2 = g2[lane] * inv, o2 = b2[lane];
#pragma unroll
  for (int al = 0; al < 2; ++al) {
    const int a_local = wv * 2 + al;
    const int n = g * GA + a_local;
    const uint32_t ysu = Yu[(size_t)n * 128 + lane];
    const int4* ir = (const int4*)(IDX + (size_t)n * 12);
    const int4 ia = ir[0], ib = ir[1], ic = ir[2];
    const int jj[12] = {ia.x, ia.y, ia.z, ia.w, ib.x, ib.y,
                        ib.z, ib.w, ic.x, ic.y, ic.z, ic.w};
    uint32_t eu[12], ynu[12];
#pragma unroll
    for (int m = 0; m < 12; ++m) {
      const int row = a_local * 12 + m;
      eu[m] = eb32[row * 64 + ((lane + row) & 63)];
      ynu[m] = Yu[(size_t)jj[m] * 128 + 64 + lane];
    }
    const float ysf = lo16(ysu), ysc = hi16(ysu);
    float acc = 0.f;
#pragma unroll
    for (int m = 0; m < 12; ++m) {
      const float flt = ysf + lo16(ynu[m]) + lo16(eu[m]);
      const float core = ysc + hi16(ynu[m]) + hi16(eu[m]);
      acc += sig(flt) * sp(core);
    }
    const size_t o = (size_t)n * 64 + lane;
    const float res = sp(X[o] + acc * s2 + o2);
    X[o] = res;
    Xb[o] = (unsigned short)f2bf(res);
  }
}

// ---------------------------------------------------------------------------
// Pool + extra embedding + FC + 3 heads.
// ---------------------------------------------------------------------------
__device__ __forceinline__ int lbound(const int* __restrict__ a, int n, int v) {
  int lo = 0, hi = n;
  while (lo < hi) {
    int mid = (lo + hi) >> 1;
    if (a[mid] < v) lo = mid + 1; else hi = mid;
  }
  return lo;
}

__global__ __launch_bounds__(128) void k_head(
    const float* __restrict__ Xf, const int* __restrict__ seg,
    const float* __restrict__ EF, const float* __restrict__ Wx,
    const float* __restrict__ bx, const float* __restrict__ gx,
    const float* __restrict__ bxb, const float* __restrict__ Wfc,
    const float* __restrict__ bfc, const float* __restrict__ Wo0,
    const float* __restrict__ bo0, const float* __restrict__ Wo1,
    const float* __restrict__ bo1, const float* __restrict__ Wo2,
    const float* __restrict__ bo2, float* __restrict__ out) {
  const int b = blockIdx.x;
  const int t = threadIdx.x;
  __shared__ float vbuf[80];
  __shared__ float part[128];
  __shared__ float4 r4[128];
  const int lo = lbound(seg, N_ATOMS, b);
  const int hi = lbound(seg, N_ATOMS, b + 1);
  const int col = t & 63, half = t >> 6;
  float s = 0.f;
  for (int r = lo + half; r < hi; r += 2) s += Xf[(size_t)r * 64 + col];
  part[t] = s;
  __syncthreads();
  if (t < 64) {
    vbuf[t] = (part[t] + part[t + 64]) / fmaxf((float)(hi - lo), 1.f);
  } else if (t < 80) {
    const int e = t - 64;
    float a = bx[e];
#pragma unroll
    for (int k = 0; k < 8; ++k) a += EF[b * 8 + k] * Wx[k * 16 + e];
    a = a * (gx[e] * rsqrtf(1.f + EPSBN)) + bxb[e];
    vbuf[t] = sp(a);
  }
  __syncthreads();
  float h = bfc[t];
#pragma unroll
  for (int k = 0; k < 80; ++k) h += vbuf[k] * Wfc[k * 128 + t];
  h = sp(h);
  r4[t] = make_float4(h * Wo0[t], h * Wo1[2 * t], h * Wo1[2 * t + 1],
                      h * Wo2[t]);
  __syncthreads();
  for (int st2 = 64; st2 > 0; st2 >>= 1) {
    if (t < st2) {
      float4 a = r4[t], c = r4[t + st2];
      r4[t] = make_float4(a.x + c.x, a.y + c.y, a.z + c.z, a.w + c.w);
    }
    __syncthreads();
  }
  if (t == 0) {
    float4 r = r4[0];
    out[b] = r.x + bo0[0];
    float z0 = r.y + bo1[0], z1 = r.z + bo1[1];
    float mx = fmaxf(z0, z1);
    float lse = mx + __logf(__expf(z0 - mx) + __expf(z1 - mx));
    out[B_CRYS + 2 * b] = z0 - lse;
    out[B_CRYS + 2 * b + 1] = z1 - lse;
    out[3 * B_CRYS + b] = r.w + bo2[0];
  }
}

// ---------------------------------------------------------------------------
extern "C" void kernel_launch(void* const* d_in, const int* in_sizes, int n_in,
                              void* d_out, int out_size, void* d_ws,
                              size_t ws_size, hipStream_t stream) {
  const float* atom_fea = (const float*)d_in[0];
  const float* nbr_fea  = (const float*)d_in[1];
  const int*   nbr_idx  = (const int*)d_in[2];
  const int*   seg      = (const int*)d_in[3];
  const float* extra    = (const float*)d_in[4];
  const float* W_embed  = (const float*)d_in[5];
  const float* b_embed  = (const float*)d_in[6];
  const float* conv_W   = (const float*)d_in[7];
  const float* conv_b   = (const float*)d_in[8];
  const float* bn1_g    = (const float*)d_in[9];
  const float* bn1_b    = (const float*)d_in[10];
  const float* bn2_g    = (const float*)d_in[11];
  const float* bn2_b    = (const float*)d_in[12];
  const float* W_extra  = (const float*)d_in[13];
  const float* b_extra  = (const float*)d_in[14];
  const float* bnx_g    = (const float*)d_in[15];
  const float* bnx_b    = (const float*)d_in[16];
  const float* W_fc     = (const float*)d_in[17];
  const float* b_fc     = (const float*)d_in[18];
  const float* W_out0   = (const float*)d_in[19];
  const float* b_out0   = (const float*)d_in[20];
  const float* W_out1   = (const float*)d_in[21];
  const float* b_out1   = (const float*)d_in[22];
  const float* W_out2   = (const float*)d_in[23];
  const float* b_out2   = (const float*)d_in[24];
  float* out = (float*)d_out;

  // ws: X f32 [3.84M] | Xb bf16 [3.84M] | Y bf16 [15.36M] | Wimg [73728]
  float* x = (float*)d_ws;
  unsigned short* xb = (unsigned short*)(x + (size_t)N_ATOMS * 64);
  unsigned short* Y = xb + (size_t)N_ATOMS * 64;
  unsigned short* Wimg = Y + (size_t)N_ATOMS * 256;

  hipLaunchKernelGGL(k_wprep, dim3((3 * WIMG_L) / 256), dim3(256), 0, stream,
                     conv_W, bn1_g, Wimg);
  hipLaunchKernelGGL(k_embed2, dim3(256), dim3(256), 0, stream, atom_fea,
                     W_embed, b_embed, x, xb);
  for (int i = 0; i < 3; ++i) {
    hipLaunchKernelGGL(k_ygemm2, dim3(256), dim3(256), 0, stream, xb,
                       Wimg + (size_t)i * WIMG_L + 8192, conv_b + i * 128,
                       bn1_g + i * 128, bn1_b + i * 128, Y);
    hipLaunchKernelGGL(k_fused2, dim3(GRID_F), dim3(256), 0, stream, x, xb,
                       (const unsigned int*)Y, nbr_fea, nbr_idx,
                       Wimg + (size_t)i * WIMG_L, bn2_g + i * 64,
                       bn2_b + i * 64);
  }
  hipLaunchKernelGGL(k_head, dim3(B_CRYS), dim3(128), 0, stream, x, seg, extra,
                     W_extra, b_extra, bnx_g, bnx_b, W_fc, b_fc, W_out0, b_out0,
                     W_out1, b_out1, W_out2, b_out2, out);
}

// Round 6
// 570.046 us; speedup vs baseline: 3.4949x; 1.2784x over previous
//
#include <hip/hip_runtime.h>
#include <math.h>
#include <stdint.h>

#define N_ATOMS 60000
#define M_NBR   12
#define NBF     41
#define B_CRYS  2048
#define EPSBN   1e-5f
#define GA      8                 // atoms per fused block
#define ROWS    (GA * M_NBR)      // 96 edge rows per block
#define GRID_F  (N_ATOMS / GA)    // 7500
#define WIMG_L  24576             // shorts per layer: [edge][self][nbr] x 8192

typedef __attribute__((ext_vector_type(8))) short bf8;
typedef __attribute__((ext_vector_type(4))) float f32x4;
#define MFMA_B16(a, b, c) __builtin_amdgcn_mfma_f32_16x16x32_bf16(a, b, c, 0, 0, 0)

__device__ __forceinline__ short f2bf(float f) {
  uint32_t u = __builtin_bit_cast(uint32_t, f);
  u += 0x7FFFu + ((u >> 16) & 1u);
  return (short)(u >> 16);
}
__device__ __forceinline__ float lo16(uint32_t u) {
  return __builtin_bit_cast(float, u << 16);
}
__device__ __forceinline__ float hi16(uint32_t u) {
  return __builtin_bit_cast(float, u & 0xFFFF0000u);
}
__device__ __forceinline__ float sp(float x) {
  return (x > 15.f) ? x : __logf(1.f + __expf(x));
}
__device__ __forceinline__ float sig(float x) {
  return 1.f / (1.f + __expf(-x));
}

// ---------------------------------------------------------------------------
// Weight-image prep: bn1-folded bf16 B-fragments, MFMA lane order.
// per layer: [which 0=edge,1=self,2=nbr][frag=ct*2+ks][lane][8]
// image col j -> orig col (j>>1) + 64*(j&1)   (flt/core pairing)
// ---------------------------------------------------------------------------
__global__ __launch_bounds__(256) void k_wprep(
    const float* __restrict__ conv_W, const float* __restrict__ bn1_g,
    unsigned short* __restrict__ Wimg) {
  const int gid = blockIdx.x * 256 + threadIdx.x;
  if (gid >= 3 * WIMG_L) return;
  const int layer = gid / WIMG_L, rem = gid % WIMG_L;
  const int which = rem / 8192, r2 = rem % 8192;
  const int frag = r2 >> 9, lane = (r2 >> 3) & 63, j = r2 & 7;
  const int ct = frag >> 1, ks = frag & 1;
  const int quad = lane >> 4, l15 = lane & 15;
  const int jc = ct * 16 + l15;
  const int oc = (jc & 1) ? (jc >> 1) + 64 : (jc >> 1);
  const float s = bn1_g[layer * 128 + oc] * rsqrtf(1.f + EPSBN);
  const int k = ks * 32 + quad * 8 + j;
  const float* Wc = conv_W + (size_t)layer * 169 * 128;
  float v = 0.f;
  if (which == 0) {
    if (k < NBF) v = Wc[(128 + k) * 128 + oc] * s;
  } else if (which == 1) {
    v = Wc[k * 128 + oc] * s;
  } else {
    v = Wc[(64 + k) * 128 + oc] * s;
  }
  Wimg[gid] = (unsigned short)f2bf(v);
}

// ---------------------------------------------------------------------------
// X = atom_fea @ W_embed + b_embed (MFMA); X fp32 + packed-dword bf16 shadow.
// ---------------------------------------------------------------------------
__global__ __launch_bounds__(256) void k_embed2(
    const float* __restrict__ A, const float* __restrict__ W,
    const float* __restrict__ bias, float* __restrict__ X,
    unsigned int* __restrict__ XbU) {
  const int lane = threadIdx.x & 63, wv = threadIdx.x >> 6;
  const int quad = lane >> 4, l15 = lane & 15;
  const int gw = blockIdx.x * 4 + wv, nw = gridDim.x * 4;
  bf8 Bf[3][4];
  float bs[4];
#pragma unroll
  for (int ct = 0; ct < 4; ++ct) {
    const int col = ct * 16 + l15;
    bs[ct] = bias[col];
#pragma unroll
    for (int ks = 0; ks < 3; ++ks) {
      bf8 b;
#pragma unroll
      for (int i = 0; i < 8; ++i) {
        const int k = ks * 32 + quad * 8 + i;
        b[i] = (k < 92) ? f2bf(W[k * 64 + col]) : (short)0;
      }
      Bf[ks][ct] = b;
    }
  }
  for (int rt = gw; rt < 3750; rt += nw) {
    const int rbase = rt * 16;
    const float* ar = A + (size_t)(rbase + l15) * 92;
    const float4 p0 = *(const float4*)(ar + quad * 8);
    const float4 p1 = *(const float4*)(ar + quad * 8 + 4);
    const float4 p2 = *(const float4*)(ar + 32 + quad * 8);
    const float4 p3 = *(const float4*)(ar + 32 + quad * 8 + 4);
    bf8 A0, A1, A2;
    A0[0] = f2bf(p0.x); A0[1] = f2bf(p0.y); A0[2] = f2bf(p0.z); A0[3] = f2bf(p0.w);
    A0[4] = f2bf(p1.x); A0[5] = f2bf(p1.y); A0[6] = f2bf(p1.z); A0[7] = f2bf(p1.w);
    A1[0] = f2bf(p2.x); A1[1] = f2bf(p2.y); A1[2] = f2bf(p2.z); A1[3] = f2bf(p2.w);
    A1[4] = f2bf(p3.x); A1[5] = f2bf(p3.y); A1[6] = f2bf(p3.z); A1[7] = f2bf(p3.w);
#pragma unroll
    for (int i = 0; i < 8; ++i) {
      const int k = 64 + quad * 8 + i;
      A2[i] = (k < 92) ? f2bf(ar[k]) : (short)0;
    }
    const f32x4 z = {0.f, 0.f, 0.f, 0.f};
    f32x4 acc[4];
#pragma unroll
    for (int ct = 0; ct < 4; ++ct) {
      acc[ct] = MFMA_B16(A0, Bf[0][ct], z);
      acc[ct] = MFMA_B16(A1, Bf[1][ct], acc[ct]);
      acc[ct] = MFMA_B16(A2, Bf[2][ct], acc[ct]);
    }
#pragma unroll
    for (int ct = 0; ct < 4; ++ct)
#pragma unroll
      for (int r = 0; r < 4; ++r) {
        const int row = rbase + quad * 4 + r;
        const float v = acc[ct][r] + bs[ct];
        X[(size_t)row * 64 + ct * 16 + l15] = v;
        const unsigned int u = (unsigned short)f2bf(v);
        const unsigned int p = __shfl_xor((int)u, 1);
        if (!(l15 & 1))
          XbU[(size_t)row * 32 + ct * 8 + (l15 >> 1)] = u | (p << 16);
      }
  }
}

// ---------------------------------------------------------------------------
// Ysu[60000, 64 dwords] = self-gate: (Xb @ W_self)*s1 + (b*s1+b1), bf16 pair
// per dword (lo=flt col c, hi=core col c). Packed dword stores via shfl.
// ---------------------------------------------------------------------------
__global__ __launch_bounds__(256) void k_ygemm3(
    const unsigned short* __restrict__ Xb,
    const unsigned short* __restrict__ WiS, const float* __restrict__ bc,
    const float* __restrict__ g1, const float* __restrict__ b1,
    unsigned int* __restrict__ Ysu) {
  const int lane = threadIdx.x & 63, wv = threadIdx.x >> 6;
  const int quad = lane >> 4, l15 = lane & 15;
  const int gw = blockIdx.x * 4 + wv, nw = gridDim.x * 4;
  const float inv = rsqrtf(1.f + EPSBN);
  bf8 Bf[2][8];
  float bs[8];
#pragma unroll
  for (int ct = 0; ct < 8; ++ct) {
    const int j = ct * 16 + l15;
    const int oc = (j & 1) ? (j >> 1) + 64 : (j >> 1);
    bs[ct] = bc[oc] * (g1[oc] * inv) + b1[oc];
#pragma unroll
    for (int ks = 0; ks < 2; ++ks)
      Bf[ks][ct] = *(const bf8*)(WiS + ((ct * 2 + ks) * 64 + lane) * 8);
  }
  for (int rt = gw; rt < 3750; rt += nw) {
    const int rbase = rt * 16;
    const unsigned short* xr = Xb + (size_t)(rbase + l15) * 64;
    const bf8 A0 = *(const bf8*)(xr + quad * 8);
    const bf8 A1 = *(const bf8*)(xr + 32 + quad * 8);
    const f32x4 z = {0.f, 0.f, 0.f, 0.f};
#pragma unroll
    for (int ct = 0; ct < 8; ++ct) {
      f32x4 acc = MFMA_B16(A0, Bf[0][ct], z);
      acc = MFMA_B16(A1, Bf[1][ct], acc);
#pragma unroll
      for (int r = 0; r < 4; ++r) {
        const unsigned int u = (unsigned short)f2bf(acc[r] + bs[ct]);
        const unsigned int p = __shfl_xor((int)u, 1);
        if (!(l15 & 1))
          Ysu[(size_t)(rbase + quad * 4 + r) * 64 + ct * 8 + (l15 >> 1)] =
              u | (p << 16);
      }
    }
  }
}

// ---------------------------------------------------------------------------
// FUSED: per block (8 atoms / 96 edges):
//   gate[e,:] = nbr_fea[e]@W_edge*s1 + XbIn[idx[e]]@W_nbr*s1  (MFMA, 1 round)
//     -> LDS bf16 pairs (swizzled)
//   tail: gate += Ys[n]; acc = sum_m sig(flt)*sp(core);
//         X[n] = sp(X[n] + acc*s2 + b2); XbOut packed-dword shadow.
// XbIn / XbOut are DISTINCT buffers (cross-block gather vs own-row write —
// same-buffer would race across workgroups; G16).
// ---------------------------------------------------------------------------
__global__ __launch_bounds__(256, 5) void k_fused3(
    float* __restrict__ X, const unsigned short* __restrict__ XbIn,
    unsigned int* __restrict__ XbOutU, const unsigned int* __restrict__ Ysu,
    const float* __restrict__ NF, const int* __restrict__ IDX,
    const unsigned short* __restrict__ Wi, const float* __restrict__ g2,
    const float* __restrict__ b2) {
  __shared__ __align__(16) unsigned int eb32[ROWS * 64];  // 24576 B
  unsigned short* eb16 = (unsigned short*)eb32;
  float* stage = (float*)eb32;  // first 3936 floats = 96x41 tile
  const int tid = threadIdx.x;
  const int lane = tid & 63, wv = tid >> 6;
  const int quad = lane >> 4, l15 = lane & 15;
  const int g = blockIdx.x;
  const int ntile = (wv < 2) ? 2 : 1;  // 6 row-tiles over 4 waves

  // ---- neighbor-row A-fragments: 16B gathers from XbIn (issue early) ----
  bf8 Ax0[2], Ax1[2];
#pragma unroll
  for (int ti = 0; ti < 2; ++ti) {
    if (ti < ntile) {
      const int rbase = (wv + ti * 4) * 16;
      const int jr = IDX[g * ROWS + rbase + l15];
      const unsigned short* xr = XbIn + (size_t)jr * 64 + quad * 8;
      Ax0[ti] = *(const bf8*)xr;
      Ax1[ti] = *(const bf8*)(xr + 32);
    }
  }

  // ---- stage 96x41 f32 nbr_fea tile into LDS, coalesced ----
  const float4* s4 = (const float4*)(NF + (size_t)g * (ROWS * NBF));
#pragma unroll
  for (int it = 0; it < 4; ++it) {
    const int w = tid + it * 256;
    if (w < (ROWS * NBF) / 4) ((float4*)stage)[w] = s4[w];
  }
  __syncthreads();

  // ---- edge A-fragments from LDS ----
  bf8 Ae0[2], Ae1[2];
#pragma unroll
  for (int ti = 0; ti < 2; ++ti) {
    if (ti < ntile) {
      const int rbase = (wv + ti * 4) * 16;
      const float* rp = stage + (rbase + l15) * NBF;
      bf8 a0, a1;
#pragma unroll
      for (int i = 0; i < 8; ++i) a0[i] = f2bf(rp[quad * 8 + i]);
      if (quad == 0) {
#pragma unroll
        for (int i = 0; i < 8; ++i) a1[i] = f2bf(rp[32 + i]);
      } else if (quad == 1) {
        a1[0] = f2bf(rp[40]);
#pragma unroll
        for (int i = 1; i < 8; ++i) a1[i] = 0;
      } else {
#pragma unroll
        for (int i = 0; i < 8; ++i) a1[i] = 0;
      }
      Ae0[ti] = a0;
      Ae1[ti] = a1;
    }
  }
  __syncthreads();

  // ---- MFMA (edge + neighbor) + swizzled bf16-pair epilogue into LDS ----
#pragma unroll
  for (int ti = 0; ti < 2; ++ti) {
    if (ti < ntile) {
      const int rbase = (wv + ti * 4) * 16;
      const f32x4 z = {0.f, 0.f, 0.f, 0.f};
#pragma unroll 1
      for (int ct = 0; ct < 8; ++ct) {
        const bf8 Be0 = *(const bf8*)(Wi + ((ct * 2 + 0) * 64 + lane) * 8);
        const bf8 Be1 = *(const bf8*)(Wi + ((ct * 2 + 1) * 64 + lane) * 8);
        const bf8 Bn0 =
            *(const bf8*)(Wi + 16384 + ((ct * 2 + 0) * 64 + lane) * 8);
        const bf8 Bn1 =
            *(const bf8*)(Wi + 16384 + ((ct * 2 + 1) * 64 + lane) * 8);
        f32x4 acc = MFMA_B16(Ax0[ti], Bn0, z);
        acc = MFMA_B16(Ax1[ti], Bn1, acc);
        acc = MFMA_B16(Ae0[ti], Be0, acc);
        acc = MFMA_B16(Ae1[ti], Be1, acc);
        const int j = ct * 16 + l15;
        const int c = j >> 1, h = j & 1;
#pragma unroll
        for (int r = 0; r < 4; ++r) {
          const int row = rbase + quad * 4 + r;
          eb16[row * 128 + ((c + row) & 63) * 2 + h] =
              (unsigned short)f2bf(acc[r]);
        }
      }
    }
  }
  __syncthreads();

  // ---- tail: 2 atoms per wave ----
  const float inv = rsqrtf(1.f + EPSBN);
  const float s2 = g2[lane] * inv, o2 = b2[lane];
#pragma unroll
  for (int al = 0; al < 2; ++al) {
    const int a_local = wv * 2 + al;
    const int n = g * GA + a_local;
    const uint32_t ys = Ysu[(size_t)n * 64 + lane];
    const float ysf = lo16(ys), ysc = hi16(ys);
    float acc = 0.f;
#pragma unroll
    for (int m = 0; m < 12; ++m) {
      const int row = a_local * 12 + m;
      const uint32_t eu = eb32[row * 64 + ((lane + row) & 63)];
      acc += sig(ysf + lo16(eu)) * sp(ysc + hi16(eu));
    }
    const size_t o = (size_t)n * 64 + lane;
    const float res = sp(X[o] + acc * s2 + o2);
    X[o] = res;
    const unsigned int u = (unsigned short)f2bf(res);
    const unsigned int p = __shfl_xor((int)u, 1);
    if (!(lane & 1)) XbOutU[(size_t)n * 32 + (lane >> 1)] = u | (p << 16);
  }
}

// ---------------------------------------------------------------------------
// Pool + extra embedding + FC + 3 heads (unchanged).
// ---------------------------------------------------------------------------
__device__ __forceinline__ int lbound(const int* __restrict__ a, int n, int v) {
  int lo = 0, hi = n;
  while (lo < hi) {
    int mid = (lo + hi) >> 1;
    if (a[mid] < v) lo = mid + 1; else hi = mid;
  }
  return lo;
}

__global__ __launch_bounds__(128) void k_head(
    const float* __restrict__ Xf, const int* __restrict__ seg,
    const float* __restrict__ EF, const float* __restrict__ Wx,
    const float* __restrict__ bx, const float* __restrict__ gx,
    const float* __restrict__ bxb, const float* __restrict__ Wfc,
    const float* __restrict__ bfc, const float* __restrict__ Wo0,
    const float* __restrict__ bo0, const float* __restrict__ Wo1,
    const float* __restrict__ bo1, const float* __restrict__ Wo2,
    const float* __restrict__ bo2, float* __restrict__ out) {
  const int b = blockIdx.x;
  const int t = threadIdx.x;
  __shared__ float vbuf[80];
  __shared__ float part[128];
  __shared__ float4 r4[128];
  const int lo = lbound(seg, N_ATOMS, b);
  const int hi = lbound(seg, N_ATOMS, b + 1);
  const int col = t & 63, half = t >> 6;
  float s = 0.f;
  for (int r = lo + half; r < hi; r += 2) s += Xf[(size_t)r * 64 + col];
  part[t] = s;
  __syncthreads();
  if (t < 64) {
    vbuf[t] = (part[t] + part[t + 64]) / fmaxf((float)(hi - lo), 1.f);
  } else if (t < 80) {
    const int e = t - 64;
    float a = bx[e];
#pragma unroll
    for (int k = 0; k < 8; ++k) a += EF[b * 8 + k] * Wx[k * 16 + e];
    a = a * (gx[e] * rsqrtf(1.f + EPSBN)) + bxb[e];
    vbuf[t] = sp(a);
  }
  __syncthreads();
  float h = bfc[t];
#pragma unroll
  for (int k = 0; k < 80; ++k) h += vbuf[k] * Wfc[k * 128 + t];
  h = sp(h);
  r4[t] = make_float4(h * Wo0[t], h * Wo1[2 * t], h * Wo1[2 * t + 1],
                      h * Wo2[t]);
  __syncthreads();
  for (int st2 = 64; st2 > 0; st2 >>= 1) {
    if (t < st2) {
      float4 a = r4[t], c = r4[t + st2];
      r4[t] = make_float4(a.x + c.x, a.y + c.y, a.z + c.z, a.w + c.w);
    }
    __syncthreads();
  }
  if (t == 0) {
    float4 r = r4[0];
    out[b] = r.x + bo0[0];
    float z0 = r.y + bo1[0], z1 = r.z + bo1[1];
    float mx = fmaxf(z0, z1);
    float lse = mx + __logf(__expf(z0 - mx) + __expf(z1 - mx));
    out[B_CRYS + 2 * b] = z0 - lse;
    out[B_CRYS + 2 * b + 1] = z1 - lse;
    out[3 * B_CRYS + b] = r.w + bo2[0];
  }
}

// ---------------------------------------------------------------------------
extern "C" void kernel_launch(void* const* d_in, const int* in_sizes, int n_in,
                              void* d_out, int out_size, void* d_ws,
                              size_t ws_size, hipStream_t stream) {
  const float* atom_fea = (const float*)d_in[0];
  const float* nbr_fea  = (const float*)d_in[1];
  const int*   nbr_idx  = (const int*)d_in[2];
  const int*   seg      = (const int*)d_in[3];
  const float* extra    = (const float*)d_in[4];
  const float* W_embed  = (const float*)d_in[5];
  const float* b_embed  = (const float*)d_in[6];
  const float* conv_W   = (const float*)d_in[7];
  const float* conv_b   = (const float*)d_in[8];
  const float* bn1_g    = (const float*)d_in[9];
  const float* bn1_b    = (const float*)d_in[10];
  const float* bn2_g    = (const float*)d_in[11];
  const float* bn2_b    = (const float*)d_in[12];
  const float* W_extra  = (const float*)d_in[13];
  const float* b_extra  = (const float*)d_in[14];
  const float* bnx_g    = (const float*)d_in[15];
  const float* bnx_b    = (const float*)d_in[16];
  const float* W_fc     = (const float*)d_in[17];
  const float* b_fc     = (const float*)d_in[18];
  const float* W_out0   = (const float*)d_in[19];
  const float* b_out0   = (const float*)d_in[20];
  const float* W_out1   = (const float*)d_in[21];
  const float* b_out1   = (const float*)d_in[22];
  const float* W_out2   = (const float*)d_in[23];
  const float* b_out2   = (const float*)d_in[24];
  float* out = (float*)d_out;

  // ws: X f32 | XbU0 | XbU1 | Ysu | Wimg = 15.36+7.68+7.68+15.36+0.15 MB
  float* x = (float*)d_ws;
  unsigned int* xbu0 = (unsigned int*)(x + (size_t)N_ATOMS * 64);
  unsigned int* xbu1 = xbu0 + (size_t)N_ATOMS * 32;
  unsigned int* ysu = xbu1 + (size_t)N_ATOMS * 32;
  unsigned short* Wimg = (unsigned short*)(ysu + (size_t)N_ATOMS * 64);

  hipLaunchKernelGGL(k_wprep, dim3((3 * WIMG_L) / 256), dim3(256), 0, stream,
                     conv_W, bn1_g, Wimg);
  hipLaunchKernelGGL(k_embed2, dim3(256), dim3(256), 0, stream, atom_fea,
                     W_embed, b_embed, x, xbu0);
  unsigned int* xin = xbu0;
  unsigned int* xout = xbu1;
  for (int i = 0; i < 3; ++i) {
    hipLaunchKernelGGL(k_ygemm3, dim3(256), dim3(256), 0, stream,
                       (const unsigned short*)xin,
                       Wimg + (size_t)i * WIMG_L + 8192, conv_b + i * 128,
                       bn1_g + i * 128, bn1_b + i * 128, ysu);
    hipLaunchKernelGGL(k_fused3, dim3(GRID_F), dim3(256), 0, stream, x,
                       (const unsigned short*)xin, xout,
                       (const unsigned int*)ysu, nbr_fea, nbr_idx,
                       Wimg + (size_t)i * WIMG_L, bn2_g + i * 64,
                       bn2_b + i * 64);
    unsigned int* tmp = xin;
    xin = xout;
    xout = tmp;
  }
  hipLaunchKernelGGL(k_head, dim3(B_CRYS), dim3(128), 0, stream, x, seg, extra,
                     W_extra, b_extra, bnx_g, bnx_b, W_fc, b_fc, W_out0, b_out0,
                     W_out1, b_out1, W_out2, b_out2, out);
}

// Round 7
// 565.198 us; speedup vs baseline: 3.5249x; 1.0086x over previous
//
#include <hip/hip_runtime.h>
#include <math.h>
#include <stdint.h>

#define N_ATOMS 60000
#define M_NBR   12
#define NBF     41
#define B_CRYS  2048
#define EPSBN   1e-5f
#define GA      8                 // atoms per fused block
#define ROWS    (GA * M_NBR)      // 96 edge rows per block
#define GRID_F  (N_ATOMS / GA)    // 7500
#define WIMG_L  24576             // shorts per layer: [edge][self][nbr] x 8192

typedef __attribute__((ext_vector_type(8))) short bf8;
typedef __attribute__((ext_vector_type(4))) float f32x4;
#define MFMA_B16(a, b, c) __builtin_amdgcn_mfma_f32_16x16x32_bf16(a, b, c, 0, 0, 0)

__device__ __forceinline__ short f2bf(float f) {
  uint32_t u = __builtin_bit_cast(uint32_t, f);
  u += 0x7FFFu + ((u >> 16) & 1u);
  return (short)(u >> 16);
}
__device__ __forceinline__ float lo16(uint32_t u) {
  return __builtin_bit_cast(float, u << 16);
}
__device__ __forceinline__ float hi16(uint32_t u) {
  return __builtin_bit_cast(float, u & 0xFFFF0000u);
}
__device__ __forceinline__ float sp(float x) {
  return (x > 15.f) ? x : __logf(1.f + __expf(x));
}
__device__ __forceinline__ float sig(float x) {
  return 1.f / (1.f + __expf(-x));
}

// ---------------------------------------------------------------------------
// Weight-image prep: bn1-folded bf16 B-fragments, MFMA lane order.
// per layer: [which 0=edge,1=self,2=nbr][frag=ct*2+ks][lane][8]
// image col j -> orig col (j>>1) + 64*(j&1)   (flt/core pairing)
// Edge image row k=41 holds the bn1-folded bias (b*s1+b1); the fused kernel
// sets A[k=41]=1.0 so bias comes out of the MFMA for free.
// ---------------------------------------------------------------------------
__global__ __launch_bounds__(256) void k_wprep(
    const float* __restrict__ conv_W, const float* __restrict__ conv_b,
    const float* __restrict__ bn1_g, const float* __restrict__ bn1_b,
    unsigned short* __restrict__ Wimg) {
  const int gid = blockIdx.x * 256 + threadIdx.x;
  if (gid >= 3 * WIMG_L) return;
  const int layer = gid / WIMG_L, rem = gid % WIMG_L;
  const int which = rem / 8192, r2 = rem % 8192;
  const int frag = r2 >> 9, lane = (r2 >> 3) & 63, j = r2 & 7;
  const int ct = frag >> 1, ks = frag & 1;
  const int quad = lane >> 4, l15 = lane & 15;
  const int jc = ct * 16 + l15;
  const int oc = (jc & 1) ? (jc >> 1) + 64 : (jc >> 1);
  const float s = bn1_g[layer * 128 + oc] * rsqrtf(1.f + EPSBN);
  const int k = ks * 32 + quad * 8 + j;
  const float* Wc = conv_W + (size_t)layer * 169 * 128;
  float v = 0.f;
  if (which == 0) {
    if (k < NBF) v = Wc[(128 + k) * 128 + oc] * s;
    else if (k == NBF) v = conv_b[layer * 128 + oc] * s + bn1_b[layer * 128 + oc];
  } else if (which == 1) {
    v = Wc[k * 128 + oc] * s;
  } else {
    v = Wc[(64 + k) * 128 + oc] * s;
  }
  Wimg[gid] = (unsigned short)f2bf(v);
}

// ---------------------------------------------------------------------------
// X = atom_fea @ W_embed + b_embed (MFMA); X fp32 + packed-dword bf16 shadow.
// ---------------------------------------------------------------------------
__global__ __launch_bounds__(256) void k_embed2(
    const float* __restrict__ A, const float* __restrict__ W,
    const float* __restrict__ bias, float* __restrict__ X,
    unsigned int* __restrict__ XbU) {
  const int lane = threadIdx.x & 63, wv = threadIdx.x >> 6;
  const int quad = lane >> 4, l15 = lane & 15;
  const int gw = blockIdx.x * 4 + wv, nw = gridDim.x * 4;
  bf8 Bf[3][4];
  float bs[4];
#pragma unroll
  for (int ct = 0; ct < 4; ++ct) {
    const int col = ct * 16 + l15;
    bs[ct] = bias[col];
#pragma unroll
    for (int ks = 0; ks < 3; ++ks) {
      bf8 b;
#pragma unroll
      for (int i = 0; i < 8; ++i) {
        const int k = ks * 32 + quad * 8 + i;
        b[i] = (k < 92) ? f2bf(W[k * 64 + col]) : (short)0;
      }
      Bf[ks][ct] = b;
    }
  }
  for (int rt = gw; rt < 3750; rt += nw) {
    const int rbase = rt * 16;
    const float* ar = A + (size_t)(rbase + l15) * 92;
    const float4 p0 = *(const float4*)(ar + quad * 8);
    const float4 p1 = *(const float4*)(ar + quad * 8 + 4);
    const float4 p2 = *(const float4*)(ar + 32 + quad * 8);
    const float4 p3 = *(const float4*)(ar + 32 + quad * 8 + 4);
    bf8 A0, A1, A2;
    A0[0] = f2bf(p0.x); A0[1] = f2bf(p0.y); A0[2] = f2bf(p0.z); A0[3] = f2bf(p0.w);
    A0[4] = f2bf(p1.x); A0[5] = f2bf(p1.y); A0[6] = f2bf(p1.z); A0[7] = f2bf(p1.w);
    A1[0] = f2bf(p2.x); A1[1] = f2bf(p2.y); A1[2] = f2bf(p2.z); A1[3] = f2bf(p2.w);
    A1[4] = f2bf(p3.x); A1[5] = f2bf(p3.y); A1[6] = f2bf(p3.z); A1[7] = f2bf(p3.w);
#pragma unroll
    for (int i = 0; i < 8; ++i) {
      const int k = 64 + quad * 8 + i;
      A2[i] = (k < 92) ? f2bf(ar[k]) : (short)0;
    }
    const f32x4 z = {0.f, 0.f, 0.f, 0.f};
    f32x4 acc[4];
#pragma unroll
    for (int ct = 0; ct < 4; ++ct) {
      acc[ct] = MFMA_B16(A0, Bf[0][ct], z);
      acc[ct] = MFMA_B16(A1, Bf[1][ct], acc[ct]);
      acc[ct] = MFMA_B16(A2, Bf[2][ct], acc[ct]);
    }
#pragma unroll
    for (int ct = 0; ct < 4; ++ct)
#pragma unroll
      for (int r = 0; r < 4; ++r) {
        const int row = rbase + quad * 4 + r;
        const float v = acc[ct][r] + bs[ct];
        X[(size_t)row * 64 + ct * 16 + l15] = v;
        const unsigned int u = (unsigned short)f2bf(v);
        const unsigned int p = __shfl_xor((int)u, 1);
        if (!(l15 & 1))
          XbU[(size_t)row * 32 + ct * 8 + (l15 >> 1)] = u | (p << 16);
      }
  }
}

// ---------------------------------------------------------------------------
// FUSED conv layer: per block (8 atoms / 96 edges):
//   gate[e,:] = nbr_fea[e]@We*s1 + bias + XbIn[idx[e]]@Wn*s1
//               + XbIn[atom(e)]@Ws*s1          (one MFMA chain, one rounding)
//     -> LDS bf16 pairs (swizzled)
//   tail: acc = sum_m sig(flt)*sp(core); X[n] = sp(X[n] + acc*s2 + b2);
//         XbOut packed-dword shadow.
// XbIn / XbOut distinct buffers (cross-block gather vs own-row write; G16).
// ---------------------------------------------------------------------------
__global__ __launch_bounds__(256, 5) void k_fused4(
    float* __restrict__ X, const unsigned short* __restrict__ XbIn,
    unsigned int* __restrict__ XbOutU, const float* __restrict__ NF,
    const int* __restrict__ IDX, const unsigned short* __restrict__ Wi,
    const float* __restrict__ g2, const float* __restrict__ b2) {
  __shared__ __align__(16) unsigned int eb32[ROWS * 64];  // 24576 B
  unsigned short* eb16 = (unsigned short*)eb32;
  float* stage = (float*)eb32;  // first 3936 floats = 96x41 tile
  const int tid = threadIdx.x;
  const int lane = tid & 63, wv = tid >> 6;
  const int quad = lane >> 4, l15 = lane & 15;
  const int g = blockIdx.x;
  const int ntile = (wv < 2) ? 2 : 1;  // 6 row-tiles over 4 waves

  // ---- neighbor + self A-fragments: 16B gathers from XbIn (issue early) ----
  bf8 Ax0[2], Ax1[2], As0[2], As1[2];
#pragma unroll
  for (int ti = 0; ti < 2; ++ti) {
    if (ti < ntile) {
      const int rbase = (wv + ti * 4) * 16;
      const int jr = IDX[g * ROWS + rbase + l15];
      const unsigned short* xr = XbIn + (size_t)jr * 64 + quad * 8;
      Ax0[ti] = *(const bf8*)xr;
      Ax1[ti] = *(const bf8*)(xr + 32);
      const int arow = g * GA + (rbase + l15) / M_NBR;
      const unsigned short* sr = XbIn + (size_t)arow * 64 + quad * 8;
      As0[ti] = *(const bf8*)sr;
      As1[ti] = *(const bf8*)(sr + 32);
    }
  }

  // ---- stage 96x41 f32 nbr_fea tile into LDS, coalesced ----
  const float4* s4 = (const float4*)(NF + (size_t)g * (ROWS * NBF));
#pragma unroll
  for (int it = 0; it < 4; ++it) {
    const int w = tid + it * 256;
    if (w < (ROWS * NBF) / 4) ((float4*)stage)[w] = s4[w];
  }
  __syncthreads();

  // ---- edge A-fragments from LDS (k=41 slot := 1.0 -> bias row) ----
  bf8 Ae0[2], Ae1[2];
#pragma unroll
  for (int ti = 0; ti < 2; ++ti) {
    if (ti < ntile) {
      const int rbase = (wv + ti * 4) * 16;
      const float* rp = stage + (rbase + l15) * NBF;
      bf8 a0, a1;
#pragma unroll
      for (int i = 0; i < 8; ++i) a0[i] = f2bf(rp[quad * 8 + i]);
      if (quad == 0) {
#pragma unroll
        for (int i = 0; i < 8; ++i) a1[i] = f2bf(rp[32 + i]);
      } else if (quad == 1) {
        a1[0] = f2bf(rp[40]);
        a1[1] = (short)0x3F80;  // bf16 1.0 at k=41 -> multiplies bias row
#pragma unroll
        for (int i = 2; i < 8; ++i) a1[i] = 0;
      } else {
#pragma unroll
        for (int i = 0; i < 8; ++i) a1[i] = 0;
      }
      Ae0[ti] = a0;
      Ae1[ti] = a1;
    }
  }
  __syncthreads();

  // ---- MFMA (edge+bias, self, neighbor) + swizzled epilogue into LDS ----
#pragma unroll
  for (int ti = 0; ti < 2; ++ti) {
    if (ti < ntile) {
      const int rbase = (wv + ti * 4) * 16;
      const f32x4 z = {0.f, 0.f, 0.f, 0.f};
#pragma unroll 1
      for (int ct = 0; ct < 8; ++ct) {
        const bf8 Be0 = *(const bf8*)(Wi + ((ct * 2 + 0) * 64 + lane) * 8);
        const bf8 Be1 = *(const bf8*)(Wi + ((ct * 2 + 1) * 64 + lane) * 8);
        const bf8 Bs0 =
            *(const bf8*)(Wi + 8192 + ((ct * 2 + 0) * 64 + lane) * 8);
        const bf8 Bs1 =
            *(const bf8*)(Wi + 8192 + ((ct * 2 + 1) * 64 + lane) * 8);
        const bf8 Bn0 =
            *(const bf8*)(Wi + 16384 + ((ct * 2 + 0) * 64 + lane) * 8);
        const bf8 Bn1 =
            *(const bf8*)(Wi + 16384 + ((ct * 2 + 1) * 64 + lane) * 8);
        f32x4 acc = MFMA_B16(Ax0[ti], Bn0, z);
        acc = MFMA_B16(Ax1[ti], Bn1, acc);
        acc = MFMA_B16(As0[ti], Bs0, acc);
        acc = MFMA_B16(As1[ti], Bs1, acc);
        acc = MFMA_B16(Ae0[ti], Be0, acc);
        acc = MFMA_B16(Ae1[ti], Be1, acc);
        const int j = ct * 16 + l15;
        const int c = j >> 1, h = j & 1;
#pragma unroll
        for (int r = 0; r < 4; ++r) {
          const int row = rbase + quad * 4 + r;
          eb16[row * 128 + ((c + row) & 63) * 2 + h] =
              (unsigned short)f2bf(acc[r]);
        }
      }
    }
  }
  __syncthreads();

  // ---- tail: 2 atoms per wave, pure activation+reduce ----
  const float inv = rsqrtf(1.f + EPSBN);
  const float s2 = g2[lane] * inv, o2 = b2[lane];
#pragma unroll
  for (int al = 0; al < 2; ++al) {
    const int a_local = wv * 2 + al;
    const int n = g * GA + a_local;
    float acc = 0.f;
#pragma unroll
    for (int m = 0; m < 12; ++m) {
      const int row = a_local * 12 + m;
      const uint32_t eu = eb32[row * 64 + ((lane + row) & 63)];
      acc += sig(lo16(eu)) * sp(hi16(eu));
    }
    const size_t o = (size_t)n * 64 + lane;
    const float res = sp(X[o] + acc * s2 + o2);
    X[o] = res;
    const unsigned int u = (unsigned short)f2bf(res);
    const unsigned int p = __shfl_xor((int)u, 1);
    if (!(lane & 1)) XbOutU[(size_t)n * 32 + (lane >> 1)] = u | (p << 16);
  }
}

// ---------------------------------------------------------------------------
// Pool + extra embedding + FC + 3 heads (unchanged).
// ---------------------------------------------------------------------------
__device__ __forceinline__ int lbound(const int* __restrict__ a, int n, int v) {
  int lo = 0, hi = n;
  while (lo < hi) {
    int mid = (lo + hi) >> 1;
    if (a[mid] < v) lo = mid + 1; else hi = mid;
  }
  return lo;
}

__global__ __launch_bounds__(128) void k_head(
    const float* __restrict__ Xf, const int* __restrict__ seg,
    const float* __restrict__ EF, const float* __restrict__ Wx,
    const float* __restrict__ bx, const float* __restrict__ gx,
    const float* __restrict__ bxb, const float* __restrict__ Wfc,
    const float* __restrict__ bfc, const float* __restrict__ Wo0,
    const float* __restrict__ bo0, const float* __restrict__ Wo1,
    const float* __restrict__ bo1, const float* __restrict__ Wo2,
    const float* __restrict__ bo2, float* __restrict__ out) {
  const int b = blockIdx.x;
  const int t = threadIdx.x;
  __shared__ float vbuf[80];
  __shared__ float part[128];
  __shared__ float4 r4[128];
  const int lo = lbound(seg, N_ATOMS, b);
  const int hi = lbound(seg, N_ATOMS, b + 1);
  const int col = t & 63, half = t >> 6;
  float s = 0.f;
  for (int r = lo + half; r < hi; r += 2) s += Xf[(size_t)r * 64 + col];
  part[t] = s;
  __syncthreads();
  if (t < 64) {
    vbuf[t] = (part[t] + part[t + 64]) / fmaxf((float)(hi - lo), 1.f);
  } else if (t < 80) {
    const int e = t - 64;
    float a = bx[e];
#pragma unroll
    for (int k = 0; k < 8; ++k) a += EF[b * 8 + k] * Wx[k * 16 + e];
    a = a * (gx[e] * rsqrtf(1.f + EPSBN)) + bxb[e];
    vbuf[t] = sp(a);
  }
  __syncthreads();
  float h = bfc[t];
#pragma unroll
  for (int k = 0; k < 80; ++k) h += vbuf[k] * Wfc[k * 128 + t];
  h = sp(h);
  r4[t] = make_float4(h * Wo0[t], h * Wo1[2 * t], h * Wo1[2 * t + 1],
                      h * Wo2[t]);
  __syncthreads();
  for (int st2 = 64; st2 > 0; st2 >>= 1) {
    if (t < st2) {
      float4 a = r4[t], c = r4[t + st2];
      r4[t] = make_float4(a.x + c.x, a.y + c.y, a.z + c.z, a.w + c.w);
    }
    __syncthreads();
  }
  if (t == 0) {
    float4 r = r4[0];
    out[b] = r.x + bo0[0];
    float z0 = r.y + bo1[0], z1 = r.z + bo1[1];
    float mx = fmaxf(z0, z1);
    float lse = mx + __logf(__expf(z0 - mx) + __expf(z1 - mx));
    out[B_CRYS + 2 * b] = z0 - lse;
    out[B_CRYS + 2 * b + 1] = z1 - lse;
    out[3 * B_CRYS + b] = r.w + bo2[0];
  }
}

// ---------------------------------------------------------------------------
extern "C" void kernel_launch(void* const* d_in, const int* in_sizes, int n_in,
                              void* d_out, int out_size, void* d_ws,
                              size_t ws_size, hipStream_t stream) {
  const float* atom_fea = (const float*)d_in[0];
  const float* nbr_fea  = (const float*)d_in[1];
  const int*   nbr_idx  = (const int*)d_in[2];
  const int*   seg      = (const int*)d_in[3];
  const float* extra    = (const float*)d_in[4];
  const float* W_embed  = (const float*)d_in[5];
  const float* b_embed  = (const float*)d_in[6];
  const float* conv_W   = (const float*)d_in[7];
  const float* conv_b   = (const float*)d_in[8];
  const float* bn1_g    = (const float*)d_in[9];
  const float* bn1_b    = (const float*)d_in[10];
  const float* bn2_g    = (const float*)d_in[11];
  const float* bn2_b    = (const float*)d_in[12];
  const float* W_extra  = (const float*)d_in[13];
  const float* b_extra  = (const float*)d_in[14];
  const float* bnx_g    = (const float*)d_in[15];
  const float* bnx_b    = (const float*)d_in[16];
  const float* W_fc     = (const float*)d_in[17];
  const float* b_fc     = (const float*)d_in[18];
  const float* W_out0   = (const float*)d_in[19];
  const float* b_out0   = (const float*)d_in[20];
  const float* W_out1   = (const float*)d_in[21];
  const float* b_out1   = (const float*)d_in[22];
  const float* W_out2   = (const float*)d_in[23];
  const float* b_out2   = (const float*)d_in[24];
  float* out = (float*)d_out;

  // ws: X f32 | XbU0 | XbU1 | Wimg = 15.36 + 7.68 + 7.68 + 0.15 MB
  float* x = (float*)d_ws;
  unsigned int* xbu0 = (unsigned int*)(x + (size_t)N_ATOMS * 64);
  unsigned int* xbu1 = xbu0 + (size_t)N_ATOMS * 32;
  unsigned short* Wimg = (unsigned short*)(xbu1 + (size_t)N_ATOMS * 32);

  hipLaunchKernelGGL(k_wprep, dim3((3 * WIMG_L) / 256), dim3(256), 0, stream,
                     conv_W, conv_b, bn1_g, bn1_b, Wimg);
  hipLaunchKernelGGL(k_embed2, dim3(960), dim3(256), 0, stream, atom_fea,
                     W_embed, b_embed, x, xbu0);
  unsigned int* xin = xbu0;
  unsigned int* xout = xbu1;
  for (int i = 0; i < 3; ++i) {
    hipLaunchKernelGGL(k_fused4, dim3(GRID_F), dim3(256), 0, stream, x,
                       (const unsigned short*)xin, xout, nbr_fea, nbr_idx,
                       Wimg + (size_t)i * WIMG_L, bn2_g + i * 64,
                       bn2_b + i * 64);
    unsigned int* tmp = xin;
    xin = xout;
    xout = tmp;
  }
  hipLaunchKernelGGL(k_head, dim3(B_CRYS), dim3(128), 0, stream, x, seg, extra,
                     W_extra, b_extra, bnx_g, bnx_b, W_fc, b_fc, W_out0, b_out0,
                     W_out1, b_out1, W_out2, b_out2, out);
}